// Round 4
// baseline (273.217 us; speedup 1.0000x reference)
//
#include <hip/hip_runtime.h>
#include <hip/hip_bf16.h>

#define B_ 2
#define T_ 2048
#define C_ 1024
#define H_ 16
#define D_ 64

typedef __attribute__((ext_vector_type(8))) short bf16x8;
typedef __attribute__((ext_vector_type(4))) float f32x4;

static __device__ __forceinline__ float bf2f(unsigned short u) {
  union { unsigned int i; float f; } c;
  c.i = ((unsigned int)u) << 16;
  return c.f;
}
static __device__ __forceinline__ unsigned short f2bf(float f) {
  union { float f; unsigned int i; } c;
  c.f = f;
  unsigned int x = c.i;
  return (unsigned short)((x + 0x7fffu + ((x >> 16) & 1u)) >> 16);  // RNE
}

// async global->LDS, 16B per lane; LDS dest = (wave-uniform base) + lane*16
static __device__ __forceinline__ void gl_lds16(const void* g, void* s) {
  __builtin_amdgcn_global_load_lds(
      (const __attribute__((address_space(1))) void*)g,
      (__attribute__((address_space(3))) void*)s, 16, 0, 0);
}

// ---------------------------------------------------------------------------
__global__ __launch_bounds__(256) void fill_kernel_f32(float* __restrict__ out,
                                                       int n, float v) {
  int i = blockIdx.x * 256 + threadIdx.x;
  if (i < n) out[i] = v;
}

// ---------------------------------------------------------------------------
// fp32 -> bf16, 8 elems/thread, vectorized.
// ---------------------------------------------------------------------------
__global__ __launch_bounds__(256) void cvt_bf16(const float* __restrict__ X,
                                                unsigned short* __restrict__ Xb) {
  int i = (blockIdx.x * 256 + threadIdx.x) * 8;
  float4 f0 = *(const float4*)(X + i);
  float4 f1 = *(const float4*)(X + i + 4);
  union { unsigned short u[8]; uint4 v; } p;
  p.u[0] = f2bf(f0.x); p.u[1] = f2bf(f0.y); p.u[2] = f2bf(f0.z); p.u[3] = f2bf(f0.w);
  p.u[4] = f2bf(f1.x); p.u[5] = f2bf(f1.y); p.u[6] = f2bf(f1.z); p.u[7] = f2bf(f1.w);
  *(uint4*)(Xb + i) = p.v;
}

// ---------------------------------------------------------------------------
// Transpose + convert: W[K][N] fp32 -> WT[N][K] bf16. 32x32 LDS tiles.
// ---------------------------------------------------------------------------
__global__ __launch_bounds__(256) void transpose_cvt(const float* __restrict__ W,
                                                     unsigned short* __restrict__ WT,
                                                     int Kd, int Nd) {
  __shared__ float tile[32][33];
  const int n0 = blockIdx.x * 32, k0 = blockIdx.y * 32;
  const int tx = threadIdx.x & 31, ty = threadIdx.x >> 5;  // ty 0..7
#pragma unroll
  for (int i = 0; i < 4; ++i)
    tile[ty + i * 8][tx] = W[(size_t)(k0 + ty + i * 8) * Nd + n0 + tx];
  __syncthreads();
#pragma unroll
  for (int i = 0; i < 4; ++i)
    WT[(size_t)(n0 + ty + i * 8) * Kd + k0 + tx] = f2bf(tile[tx][ty + i * 8]);
}

// ---------------------------------------------------------------------------
// Per-head V transpose: vP[b*T+t][h*64+d] -> vT[((b*16+h)*64+d)*2048 + t].
// ---------------------------------------------------------------------------
__global__ __launch_bounds__(256) void v_transpose(const unsigned short* __restrict__ vP,
                                                   unsigned short* __restrict__ vT) {
  __shared__ unsigned short tile[64][72];
  const int t0 = blockIdx.x * 64;
  const int bh = blockIdx.y;
  const int b = bh >> 4;
  const int srow = threadIdx.x >> 3;       // 0..31
  const int sc8 = (threadIdx.x & 7) * 8;
#pragma unroll
  for (int it = 0; it < 2; ++it) {
    int r = srow + it * 32;
    *(uint4*)&tile[r][sc8] =
        *(const uint4*)(vP + (size_t)(b * T_ + t0 + r) * 1024 + (bh & 15) * 64 + sc8);
  }
  __syncthreads();
#pragma unroll
  for (int it = 0; it < 2; ++it) {
    int dd = srow + it * 32;
    union { unsigned short u[8]; uint4 v; } o;
#pragma unroll
    for (int j = 0; j < 8; ++j) o.u[j] = tile[sc8 + j][dd];
    *(uint4*)(vT + ((size_t)bh * 64 + dd) * 2048 + t0 + sc8) = o.v;
  }
}

// ---------------------------------------------------------------------------
// MFMA GEMM: C = A(bf16)[M,K] @ BT(bf16)[N,K]^T + bias.
// 128x128 tile, BK=64, 4 waves. Staging via global_load_lds width=16 (m97):
// wave w stages 32 rows of As and Bs per K-step (4 instrs each, 8 rows/instr).
// XOR swizzle preserved by permuting the per-lane GLOBAL fetch address
// (lane l fetches global chunk (l&7)^(r&7) -> lands at LDS chunk l&7);
// coalescing unaffected (same 128B row segment per 8-lane group).
// Frag reads: b128 at chunk (g+kk*4)^(row&7) -- conflict-free (0 in PMC).
// OUT_PLANES=1 -> bf16 q/k/v planes; else fp32 out.
// ---------------------------------------------------------------------------
template <int OUT_PLANES>
__global__ __launch_bounds__(256) void mfma_gemm(
    const unsigned short* __restrict__ A,
    const unsigned short* __restrict__ BT,
    const float* __restrict__ bias,
    unsigned short* __restrict__ qP, unsigned short* __restrict__ kP,
    unsigned short* __restrict__ vP, float* __restrict__ Fout,
    int N, int K) {
  __shared__ unsigned short As[128 * 64];
  __shared__ unsigned short Bs[128 * 64];

  const int tid = threadIdx.x;
  const int w = tid >> 6, lane = tid & 63;
  const int lo = lane & 15, g = lane >> 4;
  const int wm = (w >> 1) * 64, wn = (w & 1) * 64;
  const int m0 = blockIdx.y * 128, n0 = blockIdx.x * 128;

  // per-lane staging geometry: this lane covers row lr, swizzled chunk ls=lane&7,
  // fetching global chunk j = ls ^ (lr&7).
  const int lr8 = lane >> 3;           // row within the 8-row instr span

  const f32x4 zero4 = {0.f, 0.f, 0.f, 0.f};
  f32x4 acc[4][4] = {{zero4, zero4, zero4, zero4}, {zero4, zero4, zero4, zero4},
                     {zero4, zero4, zero4, zero4}, {zero4, zero4, zero4, zero4}};

  for (int k0 = 0; k0 < K; k0 += 64) {
    __syncthreads();  // previous iteration's frag readers done
#pragma unroll
    for (int it = 0; it < 4; ++it) {
      const int base_row = w * 32 + it * 8;       // wave-uniform
      const int r = base_row + lr8;               // this lane's row
      const int j = (lane & 7) ^ (r & 7);         // global chunk for LDS chunk lane&7
      gl_lds16(A + (size_t)(m0 + r) * K + k0 + j * 8, &As[base_row * 64]);
      gl_lds16(BT + (size_t)(n0 + r) * K + k0 + j * 8, &Bs[base_row * 64]);
    }
    __syncthreads();  // drains vmcnt -> staging visible

#pragma unroll
    for (int kk = 0; kk < 2; ++kk) {
      bf16x8 af[4], bfr[4];
#pragma unroll
      for (int i = 0; i < 4; ++i) {
        int ra = wm + i * 16 + lo;
        int rb = wn + i * 16 + lo;
        af[i]  = *(const bf16x8*)&As[ra * 64 + ((g + kk * 4) ^ (ra & 7)) * 8];
        bfr[i] = *(const bf16x8*)&Bs[rb * 64 + ((g + kk * 4) ^ (rb & 7)) * 8];
      }
#pragma unroll
      for (int i = 0; i < 4; ++i)
#pragma unroll
        for (int j = 0; j < 4; ++j)
          acc[i][j] = __builtin_amdgcn_mfma_f32_16x16x32_bf16(af[i], bfr[j],
                                                              acc[i][j], 0, 0, 0);
    }
  }

  float bv[4];
#pragma unroll
  for (int j = 0; j < 4; ++j) bv[j] = bias[n0 + wn + j * 16 + lo];

  if (OUT_PLANES) {
    const int pl = n0 >> 10;
    unsigned short* P = (pl == 0) ? qP : (pl == 1) ? kP : vP;
    const int col0 = (n0 & 1023) + wn + lo;
#pragma unroll
    for (int i = 0; i < 4; ++i)
#pragma unroll
      for (int r = 0; r < 4; ++r) {
        size_t row = (size_t)(m0 + wm + i * 16 + g * 4 + r);
#pragma unroll
        for (int j = 0; j < 4; ++j)
          P[row * 1024 + col0 + j * 16] = f2bf(acc[i][j][r] + bv[j]);
      }
  } else {
#pragma unroll
    for (int i = 0; i < 4; ++i)
#pragma unroll
      for (int r = 0; r < 4; ++r) {
        size_t row = (size_t)(m0 + wm + i * 16 + g * 4 + r);
#pragma unroll
        for (int j = 0; j < 4; ++j)
          Fout[row * N + n0 + wn + j * 16 + lo] = acc[i][j][r] + bv[j];
      }
  }
}

// ---------------------------------------------------------------------------
// RoPE in place on q/k planes; q pre-scaled by 1/8 (exact in bf16).
// ---------------------------------------------------------------------------
__global__ __launch_bounds__(256) void rope_kernel(unsigned short* __restrict__ qP,
                                                   unsigned short* __restrict__ kP) {
  int idx = blockIdx.x * 256 + threadIdx.x;
  int i = idx & 31;
  int h = (idx >> 5) & 15;
  int t = (idx >> 9) & 2047;
  int b = idx >> 20;
  float inv = exp2f((float)(-2 * i) * (13.287712379549449f / 64.0f));
  float ang = (float)t * inv;
  float s, c;
  sincosf(ang, &s, &c);
  size_t base = (size_t)(b * T_ + t) * 1024 + h * D_ + i;
  float q1 = bf2f(qP[base]);
  float q2 = bf2f(qP[base + 32]);
  qP[base]      = f2bf((q1 * c - q2 * s) * 0.125f);
  qP[base + 32] = f2bf((q2 * c + q1 * s) * 0.125f);
  float k1 = bf2f(kP[base]);
  float k2 = bf2f(kP[base + 32]);
  kP[base]      = f2bf(k1 * c - k2 * s);
  kP[base + 32] = f2bf(k2 * c + k1 * s);
}

// ---------------------------------------------------------------------------
// flash v7 = v6 with K/V LDS staging DELETED (m169: don't stage cache-fit
// data). K-tile and V-tile per (b,h) are 256KB each; all 4 waves read
// identical fragment addresses -> wave 0 pulls from L2, waves 1-3 hit L1
// (K+V tile = 32KB = L1). Fragment reads are exact address substitutions of
// the v6 staging identity: Ks[row][col] == kP[(b*T+kt*64+row)*1024+h*64+col],
// VTs[row][col] == vT[(bh*64+row)*2048+kt*64+col].
//  * ZERO barriers in the k-loop: the two __syncthreads only protected
//    staging; Ps is wave-private (each wave writes/reads rows w*16..w*16+15).
//    Waves skew freely; setprio arbitration becomes meaningful.
//  * LDS = Ps only (9KB, was 27KB).
//  * XCD-chunked 1-D grid (T1): xcd=cid&7 gets bh = xcd*4..xcd*4+3 only ->
//    2MB K+V working set per XCD fits the 4MB L2 (natural mapping spreads
//    all 32 bh across every XCD = 16MB, thrash). Bijective by construction.
// Paired tiles (uniform 33 iters), swapped QK^T, b64 P-write, scalar lsum,
// epilogue: unchanged from v6.
// ---------------------------------------------------------------------------
__global__ __launch_bounds__(256) void flash_mfma7(
    unsigned short* __restrict__ qP,
    const unsigned short* __restrict__ kP,
    const unsigned short* __restrict__ vT) {
  const int cid = blockIdx.x;            // 0..511
  const int xcd = cid & 7;
  const int k6 = cid >> 3;               // 0..63
  const int bh = xcd * 4 + (k6 >> 4);    // 4 bh per XCD
  const int bx = k6 & 15;                // 0..15
  const int b = bh >> 4, h = bh & 15;
  const int tid = threadIdx.x;
  const int w = tid >> 6, lane = tid & 63;
  const int lo = lane & 15, g = lane >> 4;

  __shared__ unsigned short Ps[64][72];  // [q][key]; wave-private row bands

  const f32x4 zero4 = {0.f, 0.f, 0.f, 0.f};

  const unsigned short* kbase = kP + (size_t)b * T_ * 1024 + h * 64;
  const unsigned short* vbase = vT + (size_t)bh * 64 * 2048;

#pragma unroll
  for (int half = 0; half < 2; ++half) {
    const int qt = half ? (31 - bx) : bx;
    const int rowq0 = b * T_ + qt * 64;

    // Q fragments for this wave's 16 q-rows (B-operand of swapped QK).
    const unsigned short* qrow = qP + (size_t)(rowq0 + w * 16 + lo) * 1024 + h * 64;
    bf16x8 aq0 = *(const bf16x8*)(qrow + g * 8);
    bf16x8 aq1 = *(const bf16x8*)(qrow + 32 + g * 8);

    f32x4 oacc[4] = {zero4, zero4, zero4, zero4};  // O[q=w*16+g*4+r][d=c2*16+lo]
    float lsum = 0.f;                              // denom partial, q = w*16+lo

    for (int kt = 0; kt <= qt; ++kt) {
      // ---- swapped QK^T from global K (L1/L2-resident):
      //      sacc[ct][r] = S^T[k=ct*16+g*4+r][q=w*16+lo]
      f32x4 sacc[4] = {zero4, zero4, zero4, zero4};
      __builtin_amdgcn_s_setprio(1);
#pragma unroll
      for (int ct = 0; ct < 4; ++ct) {
        const unsigned short* kr = kbase + (size_t)(kt * 64 + ct * 16 + lo) * 1024;
        bf16x8 bk0 = *(const bf16x8*)(kr + g * 8);
        bf16x8 bk1 = *(const bf16x8*)(kr + 32 + g * 8);
        sacc[ct] = __builtin_amdgcn_mfma_f32_16x16x32_bf16(bk0, aq0, sacc[ct], 0, 0, 0);
        sacc[ct] = __builtin_amdgcn_mfma_f32_16x16x32_bf16(bk1, aq1, sacc[ct], 0, 0, 0);
      }
      __builtin_amdgcn_s_setprio(0);

      // ---- causal mask (diagonal tile only): local k > local q -> -inf
      if (kt == qt) {
#pragma unroll
        for (int ct = 0; ct < 4; ++ct)
#pragma unroll
          for (int r = 0; r < 4; ++r)
            if (ct * 16 + g * 4 + r > w * 16 + lo) sacc[ct][r] = -1e30f;
      }

      // ---- exp + lsum + vectorized P-write (k consecutive in-lane)
#pragma unroll
      for (int ct = 0; ct < 4; ++ct) {
        float p0 = __expf(sacc[ct][0]);
        float p1 = __expf(sacc[ct][1]);
        float p2 = __expf(sacc[ct][2]);
        float p3 = __expf(sacc[ct][3]);
        lsum += (p0 + p1) + (p2 + p3);
        unsigned int u0 = (unsigned int)f2bf(p0) | ((unsigned int)f2bf(p1) << 16);
        unsigned int u1 = (unsigned int)f2bf(p2) | ((unsigned int)f2bf(p3) << 16);
        uint2 pw; pw.x = u0; pw.y = u1;
        *(uint2*)&Ps[w * 16 + lo][ct * 16 + g * 4] = pw;
      }

      // ---- PV: P from LDS (same-wave write->read, in-order DS pipe),
      //      V fragments from global (L1-hit after first wave)
      bf16x8 ap0 = *(const bf16x8*)&Ps[w * 16 + lo][g * 8];
      bf16x8 ap1 = *(const bf16x8*)&Ps[w * 16 + lo][32 + g * 8];
      __builtin_amdgcn_s_setprio(1);
#pragma unroll
      for (int c2 = 0; c2 < 4; ++c2) {
        const unsigned short* vr = vbase + (size_t)(c2 * 16 + lo) * 2048 + kt * 64;
        bf16x8 bv0 = *(const bf16x8*)(vr + g * 8);
        bf16x8 bv1 = *(const bf16x8*)(vr + 32 + g * 8);
        oacc[c2] = __builtin_amdgcn_mfma_f32_16x16x32_bf16(ap0, bv0, oacc[c2], 0, 0, 0);
        oacc[c2] = __builtin_amdgcn_mfma_f32_16x16x32_bf16(ap1, bv1, oacc[c2], 0, 0, 0);
      }
      __builtin_amdgcn_s_setprio(0);
    }

    // ---- denominator: reduce over g (lanes with same lo), then per-r pickup
    lsum += __shfl_xor(lsum, 16);
    lsum += __shfl_xor(lsum, 32);   // lanes {lo,lo+16,lo+32,lo+48}: full denom

#pragma unroll
    for (int r = 0; r < 4; ++r) {
      float inv_r = 1.0f / __shfl(lsum, g * 4 + r);  // lane s holds q=w*16+s
      unsigned short* dst = qP + (size_t)(rowq0 + w * 16 + g * 4 + r) * 1024 + h * 64 + lo;
#pragma unroll
      for (int c2 = 0; c2 < 4; ++c2)
        dst[c2 * 16] = f2bf(oacc[c2][r] * inv_r);
    }
    // Ps rows are wave-private -> no barrier needed between halves either
  }
}

// ---------------------------------------------------------------------------
extern "C" void kernel_launch(void* const* d_in, const int* in_sizes, int n_in,
                              void* d_out, int out_size, void* d_ws, size_t ws_size,
                              hipStream_t stream) {
  const float *x = nullptr, *w_attn = nullptr, *b_attn = nullptr,
              *w_proj = nullptr, *b_proj = nullptr;
  for (int i = 0; i < n_in; ++i) {
    switch (in_sizes[i]) {
      case B_ * T_ * C_:  x      = (const float*)d_in[i]; break;
      case C_ * 3 * C_:   w_attn = (const float*)d_in[i]; break;
      case 3 * C_:        b_attn = (const float*)d_in[i]; break;
      case C_ * C_:       w_proj = (const float*)d_in[i]; break;
      case C_:            b_proj = (const float*)d_in[i]; break;
      default: break;
    }
  }
  float* out = (float*)d_out;
  const int nblk = (out_size + 255) / 256;

  if (!x || !w_attn || !b_attn || !w_proj || !b_proj) {
    fill_kernel_f32<<<nblk, 256, 0, stream>>>(out, out_size, 100.0f);  // SENTINEL
    return;
  }
  // ws >= 48 MB proven (rounds 10/11 fast path). Sentinel otherwise.
  if (ws_size < (size_t)48 * 1024 * 1024) {
    fill_kernel_f32<<<nblk, 256, 0, stream>>>(out, out_size, 50.0f);   // SENTINEL
    return;
  }

  // layout: q|k|v planes (24 MB) | vT (8) | xb (8) | waT (6) | wpT (2) = 48 MB
  unsigned short* qP  = (unsigned short*)d_ws;
  unsigned short* kP  = qP + (size_t)(B_ * T_) * 1024;
  unsigned short* vP  = kP + (size_t)(B_ * T_) * 1024;
  unsigned short* vT  = vP + (size_t)(B_ * T_) * 1024;
  unsigned short* xb  = vT + (size_t)(B_ * T_) * 1024;
  unsigned short* waT = xb + (size_t)(B_ * T_) * C_;
  unsigned short* wpT = waT + (size_t)C_ * 3 * C_;

  // 0) one-shot conversions: weights -> [N][K] bf16, x -> bf16
  transpose_cvt<<<dim3((3 * C_) / 32, C_ / 32), 256, 0, stream>>>(w_attn, waT, C_, 3 * C_);
  transpose_cvt<<<dim3(C_ / 32, C_ / 32), 256, 0, stream>>>(w_proj, wpT, C_, C_);
  cvt_bf16<<<(B_ * T_ * C_) / (256 * 8), 256, 0, stream>>>(x, xb);
  // 1) qkv = xb @ w_attn + b_attn (global_load_lds staging)
  mfma_gemm<1><<<dim3((3 * C_) / 128, (B_ * T_) / 128), 256, 0, stream>>>(
      xb, waT, b_attn, qP, kP, vP, nullptr, 3 * C_, C_);
  // 2) RoPE (q pre-scaled by 1/8)
  rope_kernel<<<(B_ * T_ * H_ * (D_ / 2)) / 256, 256, 0, stream>>>(qP, kP);
  // 3) V transpose for conflict-free flash access
  v_transpose<<<dim3(T_ / 64, B_ * H_), 256, 0, stream>>>(vP, vT);
  // 4) causal flash attention v7 (no K/V staging, barrier-free, XCD-chunked)
  flash_mfma7<<<dim3(512), 256, 0, stream>>>(qP, kP, vT);
  // 5) out = y @ w_proj + b_proj (fp32 out)
  mfma_gemm<0><<<dim3(C_ / 128, (B_ * T_) / 128), 256, 0, stream>>>(
      qP, wpT, b_proj, nullptr, nullptr, nullptr, out, C_, C_);
}

// Round 5
// 209.842 us; speedup vs baseline: 1.3020x; 1.3020x over previous
//
#include <hip/hip_runtime.h>
#include <hip/hip_bf16.h>

#define B_ 2
#define T_ 2048
#define C_ 1024
#define H_ 16
#define D_ 64

typedef __attribute__((ext_vector_type(8))) short bf16x8;
typedef __attribute__((ext_vector_type(4))) float f32x4;

static __device__ __forceinline__ float bf2f(unsigned short u) {
  union { unsigned int i; float f; } c;
  c.i = ((unsigned int)u) << 16;
  return c.f;
}
static __device__ __forceinline__ unsigned short f2bf(float f) {
  union { float f; unsigned int i; } c;
  c.f = f;
  unsigned int x = c.i;
  return (unsigned short)((x + 0x7fffu + ((x >> 16) & 1u)) >> 16);  // RNE
}

// async global->LDS, 16B per lane; LDS dest = (wave-uniform base) + lane*16
static __device__ __forceinline__ void gl_lds16(const void* g, void* s) {
  __builtin_amdgcn_global_load_lds(
      (const __attribute__((address_space(1))) void*)g,
      (__attribute__((address_space(3))) void*)s, 16, 0, 0);
}

// ---------------------------------------------------------------------------
__global__ __launch_bounds__(256) void fill_kernel_f32(float* __restrict__ out,
                                                       int n, float v) {
  int i = blockIdx.x * 256 + threadIdx.x;
  if (i < n) out[i] = v;
}

// ---------------------------------------------------------------------------
// fp32 -> bf16, 8 elems/thread, vectorized.
// ---------------------------------------------------------------------------
__global__ __launch_bounds__(256) void cvt_bf16(const float* __restrict__ X,
                                                unsigned short* __restrict__ Xb) {
  int i = (blockIdx.x * 256 + threadIdx.x) * 8;
  float4 f0 = *(const float4*)(X + i);
  float4 f1 = *(const float4*)(X + i + 4);
  union { unsigned short u[8]; uint4 v; } p;
  p.u[0] = f2bf(f0.x); p.u[1] = f2bf(f0.y); p.u[2] = f2bf(f0.z); p.u[3] = f2bf(f0.w);
  p.u[4] = f2bf(f1.x); p.u[5] = f2bf(f1.y); p.u[6] = f2bf(f1.z); p.u[7] = f2bf(f1.w);
  *(uint4*)(Xb + i) = p.v;
}

// ---------------------------------------------------------------------------
// Transpose + convert: W[K][N] fp32 -> WT[N][K] bf16. 32x32 LDS tiles.
// ---------------------------------------------------------------------------
__global__ __launch_bounds__(256) void transpose_cvt(const float* __restrict__ W,
                                                     unsigned short* __restrict__ WT,
                                                     int Kd, int Nd) {
  __shared__ float tile[32][33];
  const int n0 = blockIdx.x * 32, k0 = blockIdx.y * 32;
  const int tx = threadIdx.x & 31, ty = threadIdx.x >> 5;  // ty 0..7
#pragma unroll
  for (int i = 0; i < 4; ++i)
    tile[ty + i * 8][tx] = W[(size_t)(k0 + ty + i * 8) * Nd + n0 + tx];
  __syncthreads();
#pragma unroll
  for (int i = 0; i < 4; ++i)
    WT[(size_t)(n0 + ty + i * 8) * Kd + k0 + tx] = f2bf(tile[tx][ty + i * 8]);
}

// ---------------------------------------------------------------------------
// Per-head V transpose: vP[b*T+t][h*64+d] -> vT[((b*16+h)*64+d)*2048 + t].
// ---------------------------------------------------------------------------
__global__ __launch_bounds__(256) void v_transpose(const unsigned short* __restrict__ vP,
                                                   unsigned short* __restrict__ vT) {
  __shared__ unsigned short tile[64][72];
  const int t0 = blockIdx.x * 64;
  const int bh = blockIdx.y;
  const int b = bh >> 4;
  const int srow = threadIdx.x >> 3;       // 0..31
  const int sc8 = (threadIdx.x & 7) * 8;
#pragma unroll
  for (int it = 0; it < 2; ++it) {
    int r = srow + it * 32;
    *(uint4*)&tile[r][sc8] =
        *(const uint4*)(vP + (size_t)(b * T_ + t0 + r) * 1024 + (bh & 15) * 64 + sc8);
  }
  __syncthreads();
#pragma unroll
  for (int it = 0; it < 2; ++it) {
    int dd = srow + it * 32;
    union { unsigned short u[8]; uint4 v; } o;
#pragma unroll
    for (int j = 0; j < 8; ++j) o.u[j] = tile[sc8 + j][dd];
    *(uint4*)(vT + ((size_t)bh * 64 + dd) * 2048 + t0 + sc8) = o.v;
  }
}

// ---------------------------------------------------------------------------
// MFMA GEMM: C = A(bf16)[M,K] @ BT(bf16)[N,K]^T + bias.
// 128x128 tile, BK=64, 4 waves. Staging via global_load_lds width=16 (m97):
// wave w stages 32 rows of As and Bs per K-step (4 instrs each, 8 rows/instr).
// XOR swizzle preserved by permuting the per-lane GLOBAL fetch address
// (lane l fetches global chunk (l&7)^(r&7) -> lands at LDS chunk l&7);
// coalescing unaffected (same 128B row segment per 8-lane group).
// Frag reads: b128 at chunk (g+kk*4)^(row&7) -- conflict-free (0 in PMC).
// OUT_PLANES=1 -> bf16 q/k/v planes; else fp32 out.
// ---------------------------------------------------------------------------
template <int OUT_PLANES>
__global__ __launch_bounds__(256) void mfma_gemm(
    const unsigned short* __restrict__ A,
    const unsigned short* __restrict__ BT,
    const float* __restrict__ bias,
    unsigned short* __restrict__ qP, unsigned short* __restrict__ kP,
    unsigned short* __restrict__ vP, float* __restrict__ Fout,
    int N, int K) {
  __shared__ unsigned short As[128 * 64];
  __shared__ unsigned short Bs[128 * 64];

  const int tid = threadIdx.x;
  const int w = tid >> 6, lane = tid & 63;
  const int lo = lane & 15, g = lane >> 4;
  const int wm = (w >> 1) * 64, wn = (w & 1) * 64;
  const int m0 = blockIdx.y * 128, n0 = blockIdx.x * 128;

  // per-lane staging geometry: this lane covers row lr, swizzled chunk ls=lane&7,
  // fetching global chunk j = ls ^ (lr&7).
  const int lr8 = lane >> 3;           // row within the 8-row instr span

  const f32x4 zero4 = {0.f, 0.f, 0.f, 0.f};
  f32x4 acc[4][4] = {{zero4, zero4, zero4, zero4}, {zero4, zero4, zero4, zero4},
                     {zero4, zero4, zero4, zero4}, {zero4, zero4, zero4, zero4}};

  for (int k0 = 0; k0 < K; k0 += 64) {
    __syncthreads();  // previous iteration's frag readers done
#pragma unroll
    for (int it = 0; it < 4; ++it) {
      const int base_row = w * 32 + it * 8;       // wave-uniform
      const int r = base_row + lr8;               // this lane's row
      const int j = (lane & 7) ^ (r & 7);         // global chunk for LDS chunk lane&7
      gl_lds16(A + (size_t)(m0 + r) * K + k0 + j * 8, &As[base_row * 64]);
      gl_lds16(BT + (size_t)(n0 + r) * K + k0 + j * 8, &Bs[base_row * 64]);
    }
    __syncthreads();  // drains vmcnt -> staging visible

#pragma unroll
    for (int kk = 0; kk < 2; ++kk) {
      bf16x8 af[4], bfr[4];
#pragma unroll
      for (int i = 0; i < 4; ++i) {
        int ra = wm + i * 16 + lo;
        int rb = wn + i * 16 + lo;
        af[i]  = *(const bf16x8*)&As[ra * 64 + ((g + kk * 4) ^ (ra & 7)) * 8];
        bfr[i] = *(const bf16x8*)&Bs[rb * 64 + ((g + kk * 4) ^ (rb & 7)) * 8];
      }
#pragma unroll
      for (int i = 0; i < 4; ++i)
#pragma unroll
        for (int j = 0; j < 4; ++j)
          acc[i][j] = __builtin_amdgcn_mfma_f32_16x16x32_bf16(af[i], bfr[j],
                                                              acc[i][j], 0, 0, 0);
    }
  }

  float bv[4];
#pragma unroll
  for (int j = 0; j < 4; ++j) bv[j] = bias[n0 + wn + j * 16 + lo];

  if (OUT_PLANES) {
    const int pl = n0 >> 10;
    unsigned short* P = (pl == 0) ? qP : (pl == 1) ? kP : vP;
    const int col0 = (n0 & 1023) + wn + lo;
#pragma unroll
    for (int i = 0; i < 4; ++i)
#pragma unroll
      for (int r = 0; r < 4; ++r) {
        size_t row = (size_t)(m0 + wm + i * 16 + g * 4 + r);
#pragma unroll
        for (int j = 0; j < 4; ++j)
          P[row * 1024 + col0 + j * 16] = f2bf(acc[i][j][r] + bv[j]);
      }
  } else {
#pragma unroll
    for (int i = 0; i < 4; ++i)
#pragma unroll
      for (int r = 0; r < 4; ++r) {
        size_t row = (size_t)(m0 + wm + i * 16 + g * 4 + r);
#pragma unroll
        for (int j = 0; j < 4; ++j)
          Fout[row * N + n0 + wn + j * 16 + lo] = acc[i][j][r] + bv[j];
      }
  }
}

// ---------------------------------------------------------------------------
// RoPE in place on q/k planes; q pre-scaled by 1/8 (exact in bf16).
// ---------------------------------------------------------------------------
__global__ __launch_bounds__(256) void rope_kernel(unsigned short* __restrict__ qP,
                                                   unsigned short* __restrict__ kP) {
  int idx = blockIdx.x * 256 + threadIdx.x;
  int i = idx & 31;
  int h = (idx >> 5) & 15;
  int t = (idx >> 9) & 2047;
  int b = idx >> 20;
  float inv = exp2f((float)(-2 * i) * (13.287712379549449f / 64.0f));
  float ang = (float)t * inv;
  float s, c;
  sincosf(ang, &s, &c);
  size_t base = (size_t)(b * T_ + t) * 1024 + h * D_ + i;
  float q1 = bf2f(qP[base]);
  float q2 = bf2f(qP[base + 32]);
  qP[base]      = f2bf((q1 * c - q2 * s) * 0.125f);
  qP[base + 32] = f2bf((q2 * c + q1 * s) * 0.125f);
  float k1 = bf2f(kP[base]);
  float k2 = bf2f(kP[base + 32]);
  kP[base]      = f2bf(k1 * c - k2 * s);
  kP[base + 32] = f2bf(k2 * c + k1 * s);
}

// ---------------------------------------------------------------------------
// flash v8 = v6 (verified staging/barrier/prefetch structure; v7's
// staging-free global reads were 2.7x WORSE -- 2KB-stride lane scatter) with
// the q-tile doubled to 128 rows/block to amortize the dominant LDS cost:
// each wave re-reads the full K-tile (8 b128) + V-tile (8 b128) per k-iter;
// those reads now serve TWO 16-row q-bands (qs=0,1) instead of one.
// LDS cyc/wave-iter: v6 2x290=580 per equal work -> 336 here (-42%).
//  * grid 8x32 = 256 blocks, paired qt in {bx, 15-bx}: uniform 34 k-iters.
//  * K/V frag reads hoisted outside the qs loop (bk/bv reused for both bands).
//  * causal mask: skip-test is wave-uniform per band; band-0's final tile
//    (fully above diagonal) computes exp(-1e30)=0 -- correct, ~3% waste.
//  * everything else (swapped QK^T, b64 P-write, scalar lsum + shfl denom,
//    setprio, epilogue stores) is v6 indexed by qs.
// LDS: Ks 9KB + VTs 9KB + Ps[128][72] 18KB = 36.9KB. 1 block/CU.
// ---------------------------------------------------------------------------
__global__ __launch_bounds__(256) void flash_mfma8(
    unsigned short* __restrict__ qP,
    const unsigned short* __restrict__ kP,
    const unsigned short* __restrict__ vT) {
  const int bx = blockIdx.x;   // 0..7
  const int bh = blockIdx.y;   // 0..31
  const int b = bh >> 4, h = bh & 15;
  const int tid = threadIdx.x;
  const int w = tid >> 6, lane = tid & 63;
  const int lo = lane & 15, g = lane >> 4;

  __shared__ unsigned short Ks[64][72];    // [key][d]
  __shared__ unsigned short VTs[64][72];   // [d][key]
  __shared__ unsigned short Ps[128][72];   // [q][key]; wave-private row bands

  const int srow = tid >> 3;        // 0..31
  const int sc8 = (tid & 7) * 8;
  const f32x4 zero4 = {0.f, 0.f, 0.f, 0.f};

#pragma unroll
  for (int half = 0; half < 2; ++half) {
    const int qt = half ? (15 - bx) : bx;   // 128-row q-tile index, 0..15
    const int rowq0 = b * T_ + qt * 128;
    const int ktmax = 2 * qt + 1;           // last 64-row k-tile index

    // Q fragments: wave w owns q-bands w*32+qs*16 .. +15 (qs = 0,1)
    bf16x8 aq[2][2];
#pragma unroll
    for (int qs = 0; qs < 2; ++qs) {
      const unsigned short* qrow =
          qP + (size_t)(rowq0 + w * 32 + qs * 16 + lo) * 1024 + h * 64;
      aq[qs][0] = *(const bf16x8*)(qrow + g * 8);
      aq[qs][1] = *(const bf16x8*)(qrow + 32 + g * 8);
    }

    f32x4 oacc[2][4] = {{zero4, zero4, zero4, zero4},
                        {zero4, zero4, zero4, zero4}};
    float lsum[2] = {0.f, 0.f};

    uint4 kreg0, kreg1, vreg0, vreg1;
    {
      const size_t kb = (size_t)(b * T_ + srow) * 1024 + h * 64 + sc8;
      kreg0 = *(const uint4*)(kP + kb);
      kreg1 = *(const uint4*)(kP + kb + (size_t)32 * 1024);
      const size_t vb = ((size_t)bh * 64 + srow) * 2048 + sc8;
      vreg0 = *(const uint4*)(vT + vb);
      vreg1 = *(const uint4*)(vT + vb + (size_t)32 * 2048);
    }

    for (int kt = 0; kt <= ktmax; ++kt) {
      __syncthreads();   // prior readers of Ks/VTs done
      *(uint4*)&Ks[srow][sc8]       = kreg0;
      *(uint4*)&Ks[srow + 32][sc8]  = kreg1;
      *(uint4*)&VTs[srow][sc8]      = vreg0;
      *(uint4*)&VTs[srow + 32][sc8] = vreg1;
      __syncthreads();   // staging visible
      if (kt < ktmax) {
        const size_t kb = (size_t)(b * T_ + (kt + 1) * 64 + srow) * 1024 + h * 64 + sc8;
        kreg0 = *(const uint4*)(kP + kb);
        kreg1 = *(const uint4*)(kP + kb + (size_t)32 * 1024);
        const size_t vb = ((size_t)bh * 64 + srow) * 2048 + (kt + 1) * 64 + sc8;
        vreg0 = *(const uint4*)(vT + vb);
        vreg1 = *(const uint4*)(vT + vb + (size_t)32 * 2048);
      }

      // ---- swapped QK^T: sacc[qs][ct][r] = S^T[k=ct*16+g*4+r][q band qs]
      //      K frag reads shared across both q-bands.
      f32x4 sacc[2][4] = {{zero4, zero4, zero4, zero4},
                          {zero4, zero4, zero4, zero4}};
      __builtin_amdgcn_s_setprio(1);
#pragma unroll
      for (int ct = 0; ct < 4; ++ct) {
        bf16x8 bk0 = *(const bf16x8*)&Ks[ct * 16 + lo][g * 8];
        bf16x8 bk1 = *(const bf16x8*)&Ks[ct * 16 + lo][32 + g * 8];
#pragma unroll
        for (int qs = 0; qs < 2; ++qs) {
          sacc[qs][ct] = __builtin_amdgcn_mfma_f32_16x16x32_bf16(bk0, aq[qs][0],
                                                                 sacc[qs][ct], 0, 0, 0);
          sacc[qs][ct] = __builtin_amdgcn_mfma_f32_16x16x32_bf16(bk1, aq[qs][1],
                                                                 sacc[qs][ct], 0, 0, 0);
        }
      }
      __builtin_amdgcn_s_setprio(0);

      // ---- causal mask; skip-test wave-uniform per band
#pragma unroll
      for (int qs = 0; qs < 2; ++qs) {
        if (kt * 64 + 63 > qt * 128 + w * 32 + qs * 16) {
          const int qloc = qt * 128 + w * 32 + qs * 16 + lo;
#pragma unroll
          for (int ct = 0; ct < 4; ++ct)
#pragma unroll
            for (int r = 0; r < 4; ++r)
              if (kt * 64 + ct * 16 + g * 4 + r > qloc) sacc[qs][ct][r] = -1e30f;
        }
      }

      // ---- exp + lsum + vectorized P-write (k consecutive in-lane)
#pragma unroll
      for (int qs = 0; qs < 2; ++qs)
#pragma unroll
        for (int ct = 0; ct < 4; ++ct) {
          float p0 = __expf(sacc[qs][ct][0]);
          float p1 = __expf(sacc[qs][ct][1]);
          float p2 = __expf(sacc[qs][ct][2]);
          float p3 = __expf(sacc[qs][ct][3]);
          lsum[qs] += (p0 + p1) + (p2 + p3);
          unsigned int u0 = (unsigned int)f2bf(p0) | ((unsigned int)f2bf(p1) << 16);
          unsigned int u1 = (unsigned int)f2bf(p2) | ((unsigned int)f2bf(p3) << 16);
          uint2 pw; pw.x = u0; pw.y = u1;
          *(uint2*)&Ps[w * 32 + qs * 16 + lo][ct * 16 + g * 4] = pw;
        }

      // ---- PV: V frag reads shared across both q-bands
      bf16x8 ap[2][2];
#pragma unroll
      for (int qs = 0; qs < 2; ++qs) {
        ap[qs][0] = *(const bf16x8*)&Ps[w * 32 + qs * 16 + lo][g * 8];
        ap[qs][1] = *(const bf16x8*)&Ps[w * 32 + qs * 16 + lo][32 + g * 8];
      }
      __builtin_amdgcn_s_setprio(1);
#pragma unroll
      for (int c2 = 0; c2 < 4; ++c2) {
        bf16x8 bv0 = *(const bf16x8*)&VTs[c2 * 16 + lo][g * 8];
        bf16x8 bv1 = *(const bf16x8*)&VTs[c2 * 16 + lo][32 + g * 8];
#pragma unroll
        for (int qs = 0; qs < 2; ++qs) {
          oacc[qs][c2] = __builtin_amdgcn_mfma_f32_16x16x32_bf16(ap[qs][0], bv0,
                                                                 oacc[qs][c2], 0, 0, 0);
          oacc[qs][c2] = __builtin_amdgcn_mfma_f32_16x16x32_bf16(ap[qs][1], bv1,
                                                                 oacc[qs][c2], 0, 0, 0);
        }
      }
      __builtin_amdgcn_s_setprio(0);
    }

    // ---- denominator + store, per band
#pragma unroll
    for (int qs = 0; qs < 2; ++qs) {
      float ls = lsum[qs];
      ls += __shfl_xor(ls, 16);
      ls += __shfl_xor(ls, 32);   // lanes {lo, lo+16, lo+32, lo+48}: full denom
#pragma unroll
      for (int r = 0; r < 4; ++r) {
        float inv_r = 1.0f / __shfl(ls, g * 4 + r);  // lane s holds q=band+s
        unsigned short* dst =
            qP + (size_t)(rowq0 + w * 32 + qs * 16 + g * 4 + r) * 1024 + h * 64 + lo;
#pragma unroll
        for (int c2 = 0; c2 < 4; ++c2)
          dst[c2 * 16] = f2bf(oacc[qs][c2][r] * inv_r);
      }
    }
    // next half's first __syncthreads protects LDS reuse vs these stores
  }
}

// ---------------------------------------------------------------------------
extern "C" void kernel_launch(void* const* d_in, const int* in_sizes, int n_in,
                              void* d_out, int out_size, void* d_ws, size_t ws_size,
                              hipStream_t stream) {
  const float *x = nullptr, *w_attn = nullptr, *b_attn = nullptr,
              *w_proj = nullptr, *b_proj = nullptr;
  for (int i = 0; i < n_in; ++i) {
    switch (in_sizes[i]) {
      case B_ * T_ * C_:  x      = (const float*)d_in[i]; break;
      case C_ * 3 * C_:   w_attn = (const float*)d_in[i]; break;
      case 3 * C_:        b_attn = (const float*)d_in[i]; break;
      case C_ * C_:       w_proj = (const float*)d_in[i]; break;
      case C_:            b_proj = (const float*)d_in[i]; break;
      default: break;
    }
  }
  float* out = (float*)d_out;
  const int nblk = (out_size + 255) / 256;

  if (!x || !w_attn || !b_attn || !w_proj || !b_proj) {
    fill_kernel_f32<<<nblk, 256, 0, stream>>>(out, out_size, 100.0f);  // SENTINEL
    return;
  }
  // ws >= 48 MB proven (rounds 10/11 fast path). Sentinel otherwise.
  if (ws_size < (size_t)48 * 1024 * 1024) {
    fill_kernel_f32<<<nblk, 256, 0, stream>>>(out, out_size, 50.0f);   // SENTINEL
    return;
  }

  // layout: q|k|v planes (24 MB) | vT (8) | xb (8) | waT (6) | wpT (2) = 48 MB
  unsigned short* qP  = (unsigned short*)d_ws;
  unsigned short* kP  = qP + (size_t)(B_ * T_) * 1024;
  unsigned short* vP  = kP + (size_t)(B_ * T_) * 1024;
  unsigned short* vT  = vP + (size_t)(B_ * T_) * 1024;
  unsigned short* xb  = vT + (size_t)(B_ * T_) * 1024;
  unsigned short* waT = xb + (size_t)(B_ * T_) * C_;
  unsigned short* wpT = waT + (size_t)C_ * 3 * C_;

  // 0) one-shot conversions: weights -> [N][K] bf16, x -> bf16
  transpose_cvt<<<dim3((3 * C_) / 32, C_ / 32), 256, 0, stream>>>(w_attn, waT, C_, 3 * C_);
  transpose_cvt<<<dim3(C_ / 32, C_ / 32), 256, 0, stream>>>(w_proj, wpT, C_, C_);
  cvt_bf16<<<(B_ * T_ * C_) / (256 * 8), 256, 0, stream>>>(x, xb);
  // 1) qkv = xb @ w_attn + b_attn (global_load_lds staging)
  mfma_gemm<1><<<dim3((3 * C_) / 128, (B_ * T_) / 128), 256, 0, stream>>>(
      xb, waT, b_attn, qP, kP, vP, nullptr, 3 * C_, C_);
  // 2) RoPE (q pre-scaled by 1/8)
  rope_kernel<<<(B_ * T_ * H_ * (D_ / 2)) / 256, 256, 0, stream>>>(qP, kP);
  // 3) V transpose for conflict-free flash staging
  v_transpose<<<dim3(T_ / 64, B_ * H_), 256, 0, stream>>>(vP, vT);
  // 4) causal flash attention v8 (128-row q-tile, amortized K/V reads)
  flash_mfma8<<<dim3(8, B_ * H_), 256, 0, stream>>>(qP, kP, vT);
  // 5) out = y @ w_proj + b_proj (fp32 out)
  mfma_gemm<0><<<dim3(C_ / 128, (B_ * T_) / 128), 256, 0, stream>>>(
      qP, wpT, b_proj, nullptr, nullptr, nullptr, out, C_, C_);
}

// Round 6
// 203.080 us; speedup vs baseline: 1.3454x; 1.0333x over previous
//
#include <hip/hip_runtime.h>
#include <hip/hip_bf16.h>

#define B_ 2
#define T_ 2048
#define C_ 1024
#define H_ 16
#define D_ 64

typedef __attribute__((ext_vector_type(8))) short bf16x8;
typedef __attribute__((ext_vector_type(4))) float f32x4;

static __device__ __forceinline__ float bf2f(unsigned short u) {
  union { unsigned int i; float f; } c;
  c.i = ((unsigned int)u) << 16;
  return c.f;
}
static __device__ __forceinline__ unsigned short f2bf(float f) {
  union { float f; unsigned int i; } c;
  c.f = f;
  unsigned int x = c.i;
  return (unsigned short)((x + 0x7fffu + ((x >> 16) & 1u)) >> 16);  // RNE
}

// async global->LDS, 16B per lane; LDS dest = (wave-uniform base) + lane*16
static __device__ __forceinline__ void gl_lds16(const void* g, void* s) {
  __builtin_amdgcn_global_load_lds(
      (const __attribute__((address_space(1))) void*)g,
      (__attribute__((address_space(3))) void*)s, 16, 0, 0);
}

// ---------------------------------------------------------------------------
__global__ __launch_bounds__(256) void fill_kernel_f32(float* __restrict__ out,
                                                       int n, float v) {
  int i = blockIdx.x * 256 + threadIdx.x;
  if (i < n) out[i] = v;
}

// ---------------------------------------------------------------------------
// fp32 -> bf16, 8 elems/thread, vectorized.
// ---------------------------------------------------------------------------
__global__ __launch_bounds__(256) void cvt_bf16(const float* __restrict__ X,
                                                unsigned short* __restrict__ Xb) {
  int i = (blockIdx.x * 256 + threadIdx.x) * 8;
  float4 f0 = *(const float4*)(X + i);
  float4 f1 = *(const float4*)(X + i + 4);
  union { unsigned short u[8]; uint4 v; } p;
  p.u[0] = f2bf(f0.x); p.u[1] = f2bf(f0.y); p.u[2] = f2bf(f0.z); p.u[3] = f2bf(f0.w);
  p.u[4] = f2bf(f1.x); p.u[5] = f2bf(f1.y); p.u[6] = f2bf(f1.z); p.u[7] = f2bf(f1.w);
  *(uint4*)(Xb + i) = p.v;
}

// ---------------------------------------------------------------------------
// Transpose + convert: W[K][N] fp32 -> WT[N][K] bf16. 32x32 LDS tiles.
// ---------------------------------------------------------------------------
__global__ __launch_bounds__(256) void transpose_cvt(const float* __restrict__ W,
                                                     unsigned short* __restrict__ WT,
                                                     int Kd, int Nd) {
  __shared__ float tile[32][33];
  const int n0 = blockIdx.x * 32, k0 = blockIdx.y * 32;
  const int tx = threadIdx.x & 31, ty = threadIdx.x >> 5;  // ty 0..7
#pragma unroll
  for (int i = 0; i < 4; ++i)
    tile[ty + i * 8][tx] = W[(size_t)(k0 + ty + i * 8) * Nd + n0 + tx];
  __syncthreads();
#pragma unroll
  for (int i = 0; i < 4; ++i)
    WT[(size_t)(n0 + ty + i * 8) * Kd + k0 + tx] = f2bf(tile[tx][ty + i * 8]);
}

// ---------------------------------------------------------------------------
// Per-head V transpose: vP[b*T+t][h*64+d] -> vT[((b*16+h)*64+d)*2048 + t].
// ---------------------------------------------------------------------------
__global__ __launch_bounds__(256) void v_transpose(const unsigned short* __restrict__ vP,
                                                   unsigned short* __restrict__ vT) {
  __shared__ unsigned short tile[64][72];
  const int t0 = blockIdx.x * 64;
  const int bh = blockIdx.y;
  const int b = bh >> 4;
  const int srow = threadIdx.x >> 3;       // 0..31
  const int sc8 = (threadIdx.x & 7) * 8;
#pragma unroll
  for (int it = 0; it < 2; ++it) {
    int r = srow + it * 32;
    *(uint4*)&tile[r][sc8] =
        *(const uint4*)(vP + (size_t)(b * T_ + t0 + r) * 1024 + (bh & 15) * 64 + sc8);
  }
  __syncthreads();
#pragma unroll
  for (int it = 0; it < 2; ++it) {
    int dd = srow + it * 32;
    union { unsigned short u[8]; uint4 v; } o;
#pragma unroll
    for (int j = 0; j < 8; ++j) o.u[j] = tile[sc8 + j][dd];
    *(uint4*)(vT + ((size_t)bh * 64 + dd) * 2048 + t0 + sc8) = o.v;
  }
}

// ---------------------------------------------------------------------------
// MFMA GEMM: C = A(bf16)[M,K] @ BT(bf16)[N,K]^T + bias.
// 128x128 tile, BK=64, 4 waves. Staging via global_load_lds width=16 (m97).
// OUT_PLANES=1 -> bf16 q/k/v planes WITH RoPE FUSED into the q/k epilogue:
// a thread holds cols {lo, lo+16, lo+32, lo+48} of ONE 64-col head window
// (planes are 1024-wide, tiles 128-wide -> never straddle a plane), i.e.
// exactly the RoPE pairs (d, d+32) = (j0,j2) freq-idx lo and (j1,j3)
// freq-idx lo+16, all in-register. Same math/constants as the verified
// rope_kernel (q pre-scaled by 1/8), applied to fp32 acc+bias pre-rounding.
// OUT_PLANES=0 -> fp32 out, unchanged.
// ---------------------------------------------------------------------------
template <int OUT_PLANES>
__global__ __launch_bounds__(256) void mfma_gemm(
    const unsigned short* __restrict__ A,
    const unsigned short* __restrict__ BT,
    const float* __restrict__ bias,
    unsigned short* __restrict__ qP, unsigned short* __restrict__ kP,
    unsigned short* __restrict__ vP, float* __restrict__ Fout,
    int N, int K) {
  __shared__ unsigned short As[128 * 64];
  __shared__ unsigned short Bs[128 * 64];

  const int tid = threadIdx.x;
  const int w = tid >> 6, lane = tid & 63;
  const int lo = lane & 15, g = lane >> 4;
  const int wm = (w >> 1) * 64, wn = (w & 1) * 64;
  const int m0 = blockIdx.y * 128, n0 = blockIdx.x * 128;

  // per-lane staging geometry: this lane covers row lr, swizzled chunk ls=lane&7,
  // fetching global chunk j = ls ^ (lr&7).
  const int lr8 = lane >> 3;           // row within the 8-row instr span

  const f32x4 zero4 = {0.f, 0.f, 0.f, 0.f};
  f32x4 acc[4][4] = {{zero4, zero4, zero4, zero4}, {zero4, zero4, zero4, zero4},
                     {zero4, zero4, zero4, zero4}, {zero4, zero4, zero4, zero4}};

  for (int k0 = 0; k0 < K; k0 += 64) {
    __syncthreads();  // previous iteration's frag readers done
#pragma unroll
    for (int it = 0; it < 4; ++it) {
      const int base_row = w * 32 + it * 8;       // wave-uniform
      const int r = base_row + lr8;               // this lane's row
      const int j = (lane & 7) ^ (r & 7);         // global chunk for LDS chunk lane&7
      gl_lds16(A + (size_t)(m0 + r) * K + k0 + j * 8, &As[base_row * 64]);
      gl_lds16(BT + (size_t)(n0 + r) * K + k0 + j * 8, &Bs[base_row * 64]);
    }
    __syncthreads();  // drains vmcnt -> staging visible

#pragma unroll
    for (int kk = 0; kk < 2; ++kk) {
      bf16x8 af[4], bfr[4];
#pragma unroll
      for (int i = 0; i < 4; ++i) {
        int ra = wm + i * 16 + lo;
        int rb = wn + i * 16 + lo;
        af[i]  = *(const bf16x8*)&As[ra * 64 + ((g + kk * 4) ^ (ra & 7)) * 8];
        bfr[i] = *(const bf16x8*)&Bs[rb * 64 + ((g + kk * 4) ^ (rb & 7)) * 8];
      }
#pragma unroll
      for (int i = 0; i < 4; ++i)
#pragma unroll
        for (int j = 0; j < 4; ++j)
          acc[i][j] = __builtin_amdgcn_mfma_f32_16x16x32_bf16(af[i], bfr[j],
                                                              acc[i][j], 0, 0, 0);
    }
  }

  float bv[4];
#pragma unroll
  for (int j = 0; j < 4; ++j) bv[j] = bias[n0 + wn + j * 16 + lo];

  if (OUT_PLANES) {
    const int pl = n0 >> 10;
    const int col0 = (n0 & 1023) + wn + lo;
    if (pl == 2) {
      // ---- v plane: plain store
#pragma unroll
      for (int i = 0; i < 4; ++i)
#pragma unroll
        for (int r = 0; r < 4; ++r) {
          size_t row = (size_t)(m0 + wm + i * 16 + g * 4 + r);
#pragma unroll
          for (int j = 0; j < 4; ++j)
            vP[row * 1024 + col0 + j * 16] = f2bf(acc[i][j][r] + bv[j]);
        }
    } else {
      // ---- q/k planes: fused RoPE (verified rope_kernel math).
      unsigned short* P = (pl == 0) ? qP : kP;
      const float scale = (pl == 0) ? 0.125f : 1.0f;
      // freq idx lo for pair (j0, j2); lo+16 for pair (j1, j3)
      const float invA = exp2f((float)(-2 * lo) * (13.287712379549449f / 64.0f));
      const float invB = exp2f((float)(-2 * (lo + 16)) * (13.287712379549449f / 64.0f));
#pragma unroll
      for (int i = 0; i < 4; ++i)
#pragma unroll
        for (int r = 0; r < 4; ++r) {
          const int row = m0 + wm + i * 16 + g * 4 + r;
          const float t = (float)(row & (T_ - 1));
          float sA, cA, sB, cB;
          sincosf(t * invA, &sA, &cA);
          sincosf(t * invB, &sB, &cB);
          const float q1A = acc[i][0][r] + bv[0];
          const float q2A = acc[i][2][r] + bv[2];
          const float q1B = acc[i][1][r] + bv[1];
          const float q2B = acc[i][3][r] + bv[3];
          unsigned short* dst = P + (size_t)row * 1024 + col0;
          dst[0]  = f2bf((q1A * cA - q2A * sA) * scale);
          dst[32] = f2bf((q2A * cA + q1A * sA) * scale);
          dst[16] = f2bf((q1B * cB - q2B * sB) * scale);
          dst[48] = f2bf((q2B * cB + q1B * sB) * scale);
        }
    }
  } else {
#pragma unroll
    for (int i = 0; i < 4; ++i)
#pragma unroll
      for (int r = 0; r < 4; ++r) {
        size_t row = (size_t)(m0 + wm + i * 16 + g * 4 + r);
#pragma unroll
        for (int j = 0; j < 4; ++j)
          Fout[row * N + n0 + wn + j * 16 + lo] = acc[i][j][r] + bv[j];
      }
  }
}

// ---------------------------------------------------------------------------
// flash v6 (verified 47.8us): paired tiles (uniform 33 k-iters/block),
// swapped QK^T (S^T via mfma(K,Q)), vectorized b64 P-write, scalar lsum +
// shfl denominator, setprio around MFMA clusters, double-barrier staging
// with register prefetch. Byte-identical to round-3's flash_mfma6.
// ---------------------------------------------------------------------------
__global__ __launch_bounds__(256) void flash_mfma6(
    unsigned short* __restrict__ qP,
    const unsigned short* __restrict__ kP,
    const unsigned short* __restrict__ vT) {
  const int bx = blockIdx.x;   // 0..15
  const int bh = blockIdx.y;   // 0..31
  const int b = bh >> 4, h = bh & 15;
  const int tid = threadIdx.x;
  const int w = tid >> 6, lane = tid & 63;
  const int lo = lane & 15, g = lane >> 4;

  __shared__ unsigned short Ks[64][72];   // [key][d]
  __shared__ unsigned short VTs[64][72];  // [d][key]
  __shared__ unsigned short Ps[64][72];   // [q][key]

  const int srow = tid >> 3;        // 0..31
  const int sc8 = (tid & 7) * 8;
  const f32x4 zero4 = {0.f, 0.f, 0.f, 0.f};

#pragma unroll
  for (int half = 0; half < 2; ++half) {
    const int qt = half ? (31 - bx) : bx;
    const int rowq0 = b * T_ + qt * 64;

    // Q fragments for this wave's 16 q-rows (B-operand of swapped QK).
    const unsigned short* qrow = qP + (size_t)(rowq0 + w * 16 + lo) * 1024 + h * 64;
    bf16x8 aq0 = *(const bf16x8*)(qrow + g * 8);
    bf16x8 aq1 = *(const bf16x8*)(qrow + 32 + g * 8);

    f32x4 oacc[4] = {zero4, zero4, zero4, zero4};  // O[q=w*16+g*4+r][d=c2*16+lo]
    float lsum = 0.f;                              // denom partial, q = w*16+lo

    uint4 kreg0, kreg1, vreg0, vreg1;
    {
      const size_t kb = (size_t)(b * T_ + srow) * 1024 + h * 64 + sc8;
      kreg0 = *(const uint4*)(kP + kb);
      kreg1 = *(const uint4*)(kP + kb + (size_t)32 * 1024);
      const size_t vb = ((size_t)bh * 64 + srow) * 2048 + sc8;
      vreg0 = *(const uint4*)(vT + vb);
      vreg1 = *(const uint4*)(vT + vb + (size_t)32 * 2048);
    }

    for (int kt = 0; kt <= qt; ++kt) {
      __syncthreads();   // prior readers of Ks/VTs/Ps done
      *(uint4*)&Ks[srow][sc8]       = kreg0;
      *(uint4*)&Ks[srow + 32][sc8]  = kreg1;
      *(uint4*)&VTs[srow][sc8]      = vreg0;
      *(uint4*)&VTs[srow + 32][sc8] = vreg1;
      __syncthreads();   // staging visible
      if (kt < qt) {
        const size_t kb = (size_t)(b * T_ + (kt + 1) * 64 + srow) * 1024 + h * 64 + sc8;
        kreg0 = *(const uint4*)(kP + kb);
        kreg1 = *(const uint4*)(kP + kb + (size_t)32 * 1024);
        const size_t vb = ((size_t)bh * 64 + srow) * 2048 + (kt + 1) * 64 + sc8;
        vreg0 = *(const uint4*)(vT + vb);
        vreg1 = *(const uint4*)(vT + vb + (size_t)32 * 2048);
      }

      // ---- swapped QK^T: sacc[ct][r] = S^T[k=ct*16+g*4+r][q=w*16+lo]
      f32x4 sacc[4] = {zero4, zero4, zero4, zero4};
      __builtin_amdgcn_s_setprio(1);
#pragma unroll
      for (int ct = 0; ct < 4; ++ct) {
        bf16x8 bk0 = *(const bf16x8*)&Ks[ct * 16 + lo][g * 8];
        bf16x8 bk1 = *(const bf16x8*)&Ks[ct * 16 + lo][32 + g * 8];
        sacc[ct] = __builtin_amdgcn_mfma_f32_16x16x32_bf16(bk0, aq0, sacc[ct], 0, 0, 0);
        sacc[ct] = __builtin_amdgcn_mfma_f32_16x16x32_bf16(bk1, aq1, sacc[ct], 0, 0, 0);
      }
      __builtin_amdgcn_s_setprio(0);

      // ---- causal mask (diagonal tile only): local k > local q -> -inf
      if (kt == qt) {
#pragma unroll
        for (int ct = 0; ct < 4; ++ct)
#pragma unroll
          for (int r = 0; r < 4; ++r)
            if (ct * 16 + g * 4 + r > w * 16 + lo) sacc[ct][r] = -1e30f;
      }

      // ---- exp + lsum + vectorized P-write (k consecutive in-lane)
#pragma unroll
      for (int ct = 0; ct < 4; ++ct) {
        float p0 = __expf(sacc[ct][0]);
        float p1 = __expf(sacc[ct][1]);
        float p2 = __expf(sacc[ct][2]);
        float p3 = __expf(sacc[ct][3]);
        lsum += (p0 + p1) + (p2 + p3);
        unsigned int u0 = (unsigned int)f2bf(p0) | ((unsigned int)f2bf(p1) << 16);
        unsigned int u1 = (unsigned int)f2bf(p2) | ((unsigned int)f2bf(p3) << 16);
        uint2 pw; pw.x = u0; pw.y = u1;
        *(uint2*)&Ps[w * 16 + lo][ct * 16 + g * 4] = pw;
      }

      // ---- PV (same-wave Ps write->read, in-order DS pipe)
      bf16x8 ap0 = *(const bf16x8*)&Ps[w * 16 + lo][g * 8];
      bf16x8 ap1 = *(const bf16x8*)&Ps[w * 16 + lo][32 + g * 8];
      __builtin_amdgcn_s_setprio(1);
#pragma unroll
      for (int c2 = 0; c2 < 4; ++c2) {
        bf16x8 bv0 = *(const bf16x8*)&VTs[c2 * 16 + lo][g * 8];
        bf16x8 bv1 = *(const bf16x8*)&VTs[c2 * 16 + lo][32 + g * 8];
        oacc[c2] = __builtin_amdgcn_mfma_f32_16x16x32_bf16(ap0, bv0, oacc[c2], 0, 0, 0);
        oacc[c2] = __builtin_amdgcn_mfma_f32_16x16x32_bf16(ap1, bv1, oacc[c2], 0, 0, 0);
      }
      __builtin_amdgcn_s_setprio(0);
    }

    // ---- denominator: reduce over g (lanes with same lo), then per-r pickup
    lsum += __shfl_xor(lsum, 16);
    lsum += __shfl_xor(lsum, 32);   // lanes {lo,lo+16,lo+32,lo+48}: full denom

#pragma unroll
    for (int r = 0; r < 4; ++r) {
      float inv_r = 1.0f / __shfl(lsum, g * 4 + r);  // lane s holds q=w*16+s
      unsigned short* dst = qP + (size_t)(rowq0 + w * 16 + g * 4 + r) * 1024 + h * 64 + lo;
#pragma unroll
      for (int c2 = 0; c2 < 4; ++c2)
        dst[c2 * 16] = f2bf(oacc[c2][r] * inv_r);
    }
    // next half's first __syncthreads protects LDS reuse vs these stores
  }
}

// ---------------------------------------------------------------------------
extern "C" void kernel_launch(void* const* d_in, const int* in_sizes, int n_in,
                              void* d_out, int out_size, void* d_ws, size_t ws_size,
                              hipStream_t stream) {
  const float *x = nullptr, *w_attn = nullptr, *b_attn = nullptr,
              *w_proj = nullptr, *b_proj = nullptr;
  for (int i = 0; i < n_in; ++i) {
    switch (in_sizes[i]) {
      case B_ * T_ * C_:  x      = (const float*)d_in[i]; break;
      case C_ * 3 * C_:   w_attn = (const float*)d_in[i]; break;
      case 3 * C_:        b_attn = (const float*)d_in[i]; break;
      case C_ * C_:       w_proj = (const float*)d_in[i]; break;
      case C_:            b_proj = (const float*)d_in[i]; break;
      default: break;
    }
  }
  float* out = (float*)d_out;
  const int nblk = (out_size + 255) / 256;

  if (!x || !w_attn || !b_attn || !w_proj || !b_proj) {
    fill_kernel_f32<<<nblk, 256, 0, stream>>>(out, out_size, 100.0f);  // SENTINEL
    return;
  }
  // ws >= 48 MB proven (rounds 10/11 fast path). Sentinel otherwise.
  if (ws_size < (size_t)48 * 1024 * 1024) {
    fill_kernel_f32<<<nblk, 256, 0, stream>>>(out, out_size, 50.0f);   // SENTINEL
    return;
  }

  // layout: q|k|v planes (24 MB) | vT (8) | xb (8) | waT (6) | wpT (2) = 48 MB
  unsigned short* qP  = (unsigned short*)d_ws;
  unsigned short* kP  = qP + (size_t)(B_ * T_) * 1024;
  unsigned short* vP  = kP + (size_t)(B_ * T_) * 1024;
  unsigned short* vT  = vP + (size_t)(B_ * T_) * 1024;
  unsigned short* xb  = vT + (size_t)(B_ * T_) * 1024;
  unsigned short* waT = xb + (size_t)(B_ * T_) * C_;
  unsigned short* wpT = waT + (size_t)C_ * 3 * C_;

  // 0) one-shot conversions: weights -> [N][K] bf16, x -> bf16
  transpose_cvt<<<dim3((3 * C_) / 32, C_ / 32), 256, 0, stream>>>(w_attn, waT, C_, 3 * C_);
  transpose_cvt<<<dim3(C_ / 32, C_ / 32), 256, 0, stream>>>(w_proj, wpT, C_, C_);
  cvt_bf16<<<(B_ * T_ * C_) / (256 * 8), 256, 0, stream>>>(x, xb);
  // 1) qkv = xb @ w_attn + b_attn, RoPE fused into the q/k epilogue
  mfma_gemm<1><<<dim3((3 * C_) / 128, (B_ * T_) / 128), 256, 0, stream>>>(
      xb, waT, b_attn, qP, kP, vP, nullptr, 3 * C_, C_);
  // 2) V transpose for conflict-free flash staging
  v_transpose<<<dim3(T_ / 64, B_ * H_), 256, 0, stream>>>(vP, vT);
  // 3) causal flash attention v6 (verified 47.8us)
  flash_mfma6<<<dim3(16, B_ * H_), 256, 0, stream>>>(qP, kP, vT);
  // 4) out = y @ w_proj + b_proj (fp32 out)
  mfma_gemm<0><<<dim3(C_ / 128, (B_ * T_) / 128), 256, 0, stream>>>(
      qP, wpT, b_proj, nullptr, nullptr, nullptr, out, C_, C_);
}

// Round 7
// 191.459 us; speedup vs baseline: 1.4270x; 1.0607x over previous
//
#include <hip/hip_runtime.h>
#include <hip/hip_bf16.h>

#define B_ 2
#define T_ 2048
#define C_ 1024
#define H_ 16
#define D_ 64

typedef __attribute__((ext_vector_type(8))) short bf16x8;
typedef __attribute__((ext_vector_type(4))) float f32x4;

static __device__ __forceinline__ float bf2f(unsigned short u) {
  union { unsigned int i; float f; } c;
  c.i = ((unsigned int)u) << 16;
  return c.f;
}
static __device__ __forceinline__ unsigned short f2bf(float f) {
  union { float f; unsigned int i; } c;
  c.f = f;
  unsigned int x = c.i;
  return (unsigned short)((x + 0x7fffu + ((x >> 16) & 1u)) >> 16);  // RNE
}

// async global->LDS, 16B per lane; LDS dest = (wave-uniform base) + lane*16
static __device__ __forceinline__ void gl_lds16(const void* g, void* s) {
  __builtin_amdgcn_global_load_lds(
      (const __attribute__((address_space(1))) void*)g,
      (__attribute__((address_space(3))) void*)s, 16, 0, 0);
}

// ---------------------------------------------------------------------------
__global__ __launch_bounds__(256) void fill_kernel_f32(float* __restrict__ out,
                                                       int n, float v) {
  int i = blockIdx.x * 256 + threadIdx.x;
  if (i < n) out[i] = v;
}

// ---------------------------------------------------------------------------
// fp32 -> bf16, 8 elems/thread, vectorized.
// ---------------------------------------------------------------------------
__global__ __launch_bounds__(256) void cvt_bf16(const float* __restrict__ X,
                                                unsigned short* __restrict__ Xb) {
  int i = (blockIdx.x * 256 + threadIdx.x) * 8;
  float4 f0 = *(const float4*)(X + i);
  float4 f1 = *(const float4*)(X + i + 4);
  union { unsigned short u[8]; uint4 v; } p;
  p.u[0] = f2bf(f0.x); p.u[1] = f2bf(f0.y); p.u[2] = f2bf(f0.z); p.u[3] = f2bf(f0.w);
  p.u[4] = f2bf(f1.x); p.u[5] = f2bf(f1.y); p.u[6] = f2bf(f1.z); p.u[7] = f2bf(f1.w);
  *(uint4*)(Xb + i) = p.v;
}

// ---------------------------------------------------------------------------
// Transpose + convert: W[K][N] fp32 -> WT[N][K] bf16. 32x32 LDS tiles.
// ---------------------------------------------------------------------------
__global__ __launch_bounds__(256) void transpose_cvt(const float* __restrict__ W,
                                                     unsigned short* __restrict__ WT,
                                                     int Kd, int Nd) {
  __shared__ float tile[32][33];
  const int n0 = blockIdx.x * 32, k0 = blockIdx.y * 32;
  const int tx = threadIdx.x & 31, ty = threadIdx.x >> 5;  // ty 0..7
#pragma unroll
  for (int i = 0; i < 4; ++i)
    tile[ty + i * 8][tx] = W[(size_t)(k0 + ty + i * 8) * Nd + n0 + tx];
  __syncthreads();
#pragma unroll
  for (int i = 0; i < 4; ++i)
    WT[(size_t)(n0 + ty + i * 8) * Kd + k0 + tx] = f2bf(tile[tx][ty + i * 8]);
}

// ---------------------------------------------------------------------------
// Per-head V transpose: vP[b*T+t][h*64+d] -> vT[((b*16+h)*64+d)*2048 + t].
// ---------------------------------------------------------------------------
__global__ __launch_bounds__(256) void v_transpose(const unsigned short* __restrict__ vP,
                                                   unsigned short* __restrict__ vT) {
  __shared__ unsigned short tile[64][72];
  const int t0 = blockIdx.x * 64;
  const int bh = blockIdx.y;
  const int b = bh >> 4;
  const int srow = threadIdx.x >> 3;       // 0..31
  const int sc8 = (threadIdx.x & 7) * 8;
#pragma unroll
  for (int it = 0; it < 2; ++it) {
    int r = srow + it * 32;
    *(uint4*)&tile[r][sc8] =
        *(const uint4*)(vP + (size_t)(b * T_ + t0 + r) * 1024 + (bh & 15) * 64 + sc8);
  }
  __syncthreads();
#pragma unroll
  for (int it = 0; it < 2; ++it) {
    int dd = srow + it * 32;
    union { unsigned short u[8]; uint4 v; } o;
#pragma unroll
    for (int j = 0; j < 8; ++j) o.u[j] = tile[sc8 + j][dd];
    *(uint4*)(vT + ((size_t)bh * 64 + dd) * 2048 + t0 + sc8) = o.v;
  }
}

// ---------------------------------------------------------------------------
// MFMA GEMM: C = A(bf16)[M,K] @ BT(bf16)[N,K]^T + bias.
// 128x128 tile, BK=64, 4 waves. Staging via global_load_lds width=16 (m97).
// OUT_PLANES=1 -> bf16 q/k/v planes WITH RoPE FUSED into the q/k epilogue:
// a thread holds cols {lo, lo+16, lo+32, lo+48} of ONE 64-col head window
// (planes are 1024-wide, tiles 128-wide -> never straddle a plane), i.e.
// exactly the RoPE pairs (d, d+32) = (j0,j2) freq-idx lo and (j1,j3)
// freq-idx lo+16, all in-register. v10: trig via HW v_sin/v_cos (input in
// REVOLUTIONS, 1/2pi folded into the freq constant, fract-wrapped) -- v9's
// libm sincosf was ~6000 VALU-cyc/wave of epilogue tail (+11us on the GEMM).
// Angle error from fp32 wrap <= 2.5e-4 rad -- far below bf16 store rounding.
// OUT_PLANES=0 -> fp32 out, unchanged.
// ---------------------------------------------------------------------------
template <int OUT_PLANES>
__global__ __launch_bounds__(256) void mfma_gemm(
    const unsigned short* __restrict__ A,
    const unsigned short* __restrict__ BT,
    const float* __restrict__ bias,
    unsigned short* __restrict__ qP, unsigned short* __restrict__ kP,
    unsigned short* __restrict__ vP, float* __restrict__ Fout,
    int N, int K) {
  __shared__ unsigned short As[128 * 64];
  __shared__ unsigned short Bs[128 * 64];

  const int tid = threadIdx.x;
  const int w = tid >> 6, lane = tid & 63;
  const int lo = lane & 15, g = lane >> 4;
  const int wm = (w >> 1) * 64, wn = (w & 1) * 64;
  const int m0 = blockIdx.y * 128, n0 = blockIdx.x * 128;

  // per-lane staging geometry: this lane covers row lr, swizzled chunk ls=lane&7,
  // fetching global chunk j = ls ^ (lr&7).
  const int lr8 = lane >> 3;           // row within the 8-row instr span

  const f32x4 zero4 = {0.f, 0.f, 0.f, 0.f};
  f32x4 acc[4][4] = {{zero4, zero4, zero4, zero4}, {zero4, zero4, zero4, zero4},
                     {zero4, zero4, zero4, zero4}, {zero4, zero4, zero4, zero4}};

  for (int k0 = 0; k0 < K; k0 += 64) {
    __syncthreads();  // previous iteration's frag readers done
#pragma unroll
    for (int it = 0; it < 4; ++it) {
      const int base_row = w * 32 + it * 8;       // wave-uniform
      const int r = base_row + lr8;               // this lane's row
      const int j = (lane & 7) ^ (r & 7);         // global chunk for LDS chunk lane&7
      gl_lds16(A + (size_t)(m0 + r) * K + k0 + j * 8, &As[base_row * 64]);
      gl_lds16(BT + (size_t)(n0 + r) * K + k0 + j * 8, &Bs[base_row * 64]);
    }
    __syncthreads();  // drains vmcnt -> staging visible

#pragma unroll
    for (int kk = 0; kk < 2; ++kk) {
      bf16x8 af[4], bfr[4];
#pragma unroll
      for (int i = 0; i < 4; ++i) {
        int ra = wm + i * 16 + lo;
        int rb = wn + i * 16 + lo;
        af[i]  = *(const bf16x8*)&As[ra * 64 + ((g + kk * 4) ^ (ra & 7)) * 8];
        bfr[i] = *(const bf16x8*)&Bs[rb * 64 + ((g + kk * 4) ^ (rb & 7)) * 8];
      }
#pragma unroll
      for (int i = 0; i < 4; ++i)
#pragma unroll
        for (int j = 0; j < 4; ++j)
          acc[i][j] = __builtin_amdgcn_mfma_f32_16x16x32_bf16(af[i], bfr[j],
                                                              acc[i][j], 0, 0, 0);
    }
  }

  float bv[4];
#pragma unroll
  for (int j = 0; j < 4; ++j) bv[j] = bias[n0 + wn + j * 16 + lo];

  if (OUT_PLANES) {
    const int pl = n0 >> 10;
    const int col0 = (n0 & 1023) + wn + lo;
    if (pl == 2) {
      // ---- v plane: plain store
#pragma unroll
      for (int i = 0; i < 4; ++i)
#pragma unroll
        for (int r = 0; r < 4; ++r) {
          size_t row = (size_t)(m0 + wm + i * 16 + g * 4 + r);
#pragma unroll
          for (int j = 0; j < 4; ++j)
            vP[row * 1024 + col0 + j * 16] = f2bf(acc[i][j][r] + bv[j]);
        }
    } else {
      // ---- q/k planes: fused RoPE, HW trig (v_sin/v_cos in revolutions).
      unsigned short* P = (pl == 0) ? qP : kP;
      const float scale = (pl == 0) ? 0.125f : 1.0f;
      // rev/step constants: 1/(2pi) folded in; freq idx lo for (j0,j2),
      // lo+16 for (j1,j3)
      const float invA = exp2f((float)(-2 * lo) * (13.287712379549449f / 64.0f)) *
                         0.15915494309189535f;
      const float invB = exp2f((float)(-2 * (lo + 16)) * (13.287712379549449f / 64.0f)) *
                         0.15915494309189535f;
#pragma unroll
      for (int i = 0; i < 4; ++i)
#pragma unroll
        for (int r = 0; r < 4; ++r) {
          const int row = m0 + wm + i * 16 + g * 4 + r;
          const float t = (float)(row & (T_ - 1));
          float ra = t * invA; ra -= floorf(ra);    // [0,1) revolutions
          float rb = t * invB; rb -= floorf(rb);
          const float sA = __builtin_amdgcn_sinf(ra);
          const float cA = __builtin_amdgcn_cosf(ra);
          const float sB = __builtin_amdgcn_sinf(rb);
          const float cB = __builtin_amdgcn_cosf(rb);
          const float q1A = acc[i][0][r] + bv[0];
          const float q2A = acc[i][2][r] + bv[2];
          const float q1B = acc[i][1][r] + bv[1];
          const float q2B = acc[i][3][r] + bv[3];
          unsigned short* dst = P + (size_t)row * 1024 + col0;
          dst[0]  = f2bf((q1A * cA - q2A * sA) * scale);
          dst[32] = f2bf((q2A * cA + q1A * sA) * scale);
          dst[16] = f2bf((q1B * cB - q2B * sB) * scale);
          dst[48] = f2bf((q2B * cB + q1B * sB) * scale);
        }
    }
  } else {
#pragma unroll
    for (int i = 0; i < 4; ++i)
#pragma unroll
      for (int r = 0; r < 4; ++r) {
        size_t row = (size_t)(m0 + wm + i * 16 + g * 4 + r);
#pragma unroll
        for (int j = 0; j < 4; ++j)
          Fout[row * N + n0 + wn + j * 16 + lo] = acc[i][j][r] + bv[j];
      }
  }
}

// ---------------------------------------------------------------------------
// flash v6 (verified 47.8us): paired tiles (uniform 33 k-iters/block),
// swapped QK^T (S^T via mfma(K,Q)), vectorized b64 P-write, scalar lsum +
// shfl denominator, setprio around MFMA clusters, double-barrier staging
// with register prefetch. Byte-identical to round-3's flash_mfma6.
// ---------------------------------------------------------------------------
__global__ __launch_bounds__(256) void flash_mfma6(
    unsigned short* __restrict__ qP,
    const unsigned short* __restrict__ kP,
    const unsigned short* __restrict__ vT) {
  const int bx = blockIdx.x;   // 0..15
  const int bh = blockIdx.y;   // 0..31
  const int b = bh >> 4, h = bh & 15;
  const int tid = threadIdx.x;
  const int w = tid >> 6, lane = tid & 63;
  const int lo = lane & 15, g = lane >> 4;

  __shared__ unsigned short Ks[64][72];   // [key][d]
  __shared__ unsigned short VTs[64][72];  // [d][key]
  __shared__ unsigned short Ps[64][72];   // [q][key]

  const int srow = tid >> 3;        // 0..31
  const int sc8 = (tid & 7) * 8;
  const f32x4 zero4 = {0.f, 0.f, 0.f, 0.f};

#pragma unroll
  for (int half = 0; half < 2; ++half) {
    const int qt = half ? (31 - bx) : bx;
    const int rowq0 = b * T_ + qt * 64;

    // Q fragments for this wave's 16 q-rows (B-operand of swapped QK).
    const unsigned short* qrow = qP + (size_t)(rowq0 + w * 16 + lo) * 1024 + h * 64;
    bf16x8 aq0 = *(const bf16x8*)(qrow + g * 8);
    bf16x8 aq1 = *(const bf16x8*)(qrow + 32 + g * 8);

    f32x4 oacc[4] = {zero4, zero4, zero4, zero4};  // O[q=w*16+g*4+r][d=c2*16+lo]
    float lsum = 0.f;                              // denom partial, q = w*16+lo

    uint4 kreg0, kreg1, vreg0, vreg1;
    {
      const size_t kb = (size_t)(b * T_ + srow) * 1024 + h * 64 + sc8;
      kreg0 = *(const uint4*)(kP + kb);
      kreg1 = *(const uint4*)(kP + kb + (size_t)32 * 1024);
      const size_t vb = ((size_t)bh * 64 + srow) * 2048 + sc8;
      vreg0 = *(const uint4*)(vT + vb);
      vreg1 = *(const uint4*)(vT + vb + (size_t)32 * 2048);
    }

    for (int kt = 0; kt <= qt; ++kt) {
      __syncthreads();   // prior readers of Ks/VTs/Ps done
      *(uint4*)&Ks[srow][sc8]       = kreg0;
      *(uint4*)&Ks[srow + 32][sc8]  = kreg1;
      *(uint4*)&VTs[srow][sc8]      = vreg0;
      *(uint4*)&VTs[srow + 32][sc8] = vreg1;
      __syncthreads();   // staging visible
      if (kt < qt) {
        const size_t kb = (size_t)(b * T_ + (kt + 1) * 64 + srow) * 1024 + h * 64 + sc8;
        kreg0 = *(const uint4*)(kP + kb);
        kreg1 = *(const uint4*)(kP + kb + (size_t)32 * 1024);
        const size_t vb = ((size_t)bh * 64 + srow) * 2048 + (kt + 1) * 64 + sc8;
        vreg0 = *(const uint4*)(vT + vb);
        vreg1 = *(const uint4*)(vT + vb + (size_t)32 * 2048);
      }

      // ---- swapped QK^T: sacc[ct][r] = S^T[k=ct*16+g*4+r][q=w*16+lo]
      f32x4 sacc[4] = {zero4, zero4, zero4, zero4};
      __builtin_amdgcn_s_setprio(1);
#pragma unroll
      for (int ct = 0; ct < 4; ++ct) {
        bf16x8 bk0 = *(const bf16x8*)&Ks[ct * 16 + lo][g * 8];
        bf16x8 bk1 = *(const bf16x8*)&Ks[ct * 16 + lo][32 + g * 8];
        sacc[ct] = __builtin_amdgcn_mfma_f32_16x16x32_bf16(bk0, aq0, sacc[ct], 0, 0, 0);
        sacc[ct] = __builtin_amdgcn_mfma_f32_16x16x32_bf16(bk1, aq1, sacc[ct], 0, 0, 0);
      }
      __builtin_amdgcn_s_setprio(0);

      // ---- causal mask (diagonal tile only): local k > local q -> -inf
      if (kt == qt) {
#pragma unroll
        for (int ct = 0; ct < 4; ++ct)
#pragma unroll
          for (int r = 0; r < 4; ++r)
            if (ct * 16 + g * 4 + r > w * 16 + lo) sacc[ct][r] = -1e30f;
      }

      // ---- exp + lsum + vectorized P-write (k consecutive in-lane)
#pragma unroll
      for (int ct = 0; ct < 4; ++ct) {
        float p0 = __expf(sacc[ct][0]);
        float p1 = __expf(sacc[ct][1]);
        float p2 = __expf(sacc[ct][2]);
        float p3 = __expf(sacc[ct][3]);
        lsum += (p0 + p1) + (p2 + p3);
        unsigned int u0 = (unsigned int)f2bf(p0) | ((unsigned int)f2bf(p1) << 16);
        unsigned int u1 = (unsigned int)f2bf(p2) | ((unsigned int)f2bf(p3) << 16);
        uint2 pw; pw.x = u0; pw.y = u1;
        *(uint2*)&Ps[w * 16 + lo][ct * 16 + g * 4] = pw;
      }

      // ---- PV (same-wave Ps write->read, in-order DS pipe)
      bf16x8 ap0 = *(const bf16x8*)&Ps[w * 16 + lo][g * 8];
      bf16x8 ap1 = *(const bf16x8*)&Ps[w * 16 + lo][32 + g * 8];
      __builtin_amdgcn_s_setprio(1);
#pragma unroll
      for (int c2 = 0; c2 < 4; ++c2) {
        bf16x8 bv0 = *(const bf16x8*)&VTs[c2 * 16 + lo][g * 8];
        bf16x8 bv1 = *(const bf16x8*)&VTs[c2 * 16 + lo][32 + g * 8];
        oacc[c2] = __builtin_amdgcn_mfma_f32_16x16x32_bf16(ap0, bv0, oacc[c2], 0, 0, 0);
        oacc[c2] = __builtin_amdgcn_mfma_f32_16x16x32_bf16(ap1, bv1, oacc[c2], 0, 0, 0);
      }
      __builtin_amdgcn_s_setprio(0);
    }

    // ---- denominator: reduce over g (lanes with same lo), then per-r pickup
    lsum += __shfl_xor(lsum, 16);
    lsum += __shfl_xor(lsum, 32);   // lanes {lo,lo+16,lo+32,lo+48}: full denom

#pragma unroll
    for (int r = 0; r < 4; ++r) {
      float inv_r = 1.0f / __shfl(lsum, g * 4 + r);  // lane s holds q=w*16+s
      unsigned short* dst = qP + (size_t)(rowq0 + w * 16 + g * 4 + r) * 1024 + h * 64 + lo;
#pragma unroll
      for (int c2 = 0; c2 < 4; ++c2)
        dst[c2 * 16] = f2bf(oacc[c2][r] * inv_r);
    }
    // next half's first __syncthreads protects LDS reuse vs these stores
  }
}

// ---------------------------------------------------------------------------
extern "C" void kernel_launch(void* const* d_in, const int* in_sizes, int n_in,
                              void* d_out, int out_size, void* d_ws, size_t ws_size,
                              hipStream_t stream) {
  const float *x = nullptr, *w_attn = nullptr, *b_attn = nullptr,
              *w_proj = nullptr, *b_proj = nullptr;
  for (int i = 0; i < n_in; ++i) {
    switch (in_sizes[i]) {
      case B_ * T_ * C_:  x      = (const float*)d_in[i]; break;
      case C_ * 3 * C_:   w_attn = (const float*)d_in[i]; break;
      case 3 * C_:        b_attn = (const float*)d_in[i]; break;
      case C_ * C_:       w_proj = (const float*)d_in[i]; break;
      case C_:            b_proj = (const float*)d_in[i]; break;
      default: break;
    }
  }
  float* out = (float*)d_out;
  const int nblk = (out_size + 255) / 256;

  if (!x || !w_attn || !b_attn || !w_proj || !b_proj) {
    fill_kernel_f32<<<nblk, 256, 0, stream>>>(out, out_size, 100.0f);  // SENTINEL
    return;
  }
  // ws >= 48 MB proven (rounds 10/11 fast path). Sentinel otherwise.
  if (ws_size < (size_t)48 * 1024 * 1024) {
    fill_kernel_f32<<<nblk, 256, 0, stream>>>(out, out_size, 50.0f);   // SENTINEL
    return;
  }

  // layout: q|k|v planes (24 MB) | vT (8) | xb (8) | waT (6) | wpT (2) = 48 MB
  unsigned short* qP  = (unsigned short*)d_ws;
  unsigned short* kP  = qP + (size_t)(B_ * T_) * 1024;
  unsigned short* vP  = kP + (size_t)(B_ * T_) * 1024;
  unsigned short* vT  = vP + (size_t)(B_ * T_) * 1024;
  unsigned short* xb  = vT + (size_t)(B_ * T_) * 1024;
  unsigned short* waT = xb + (size_t)(B_ * T_) * C_;
  unsigned short* wpT = waT + (size_t)C_ * 3 * C_;

  // 0) one-shot conversions: weights -> [N][K] bf16, x -> bf16
  transpose_cvt<<<dim3((3 * C_) / 32, C_ / 32), 256, 0, stream>>>(w_attn, waT, C_, 3 * C_);
  transpose_cvt<<<dim3(C_ / 32, C_ / 32), 256, 0, stream>>>(w_proj, wpT, C_, C_);
  cvt_bf16<<<(B_ * T_ * C_) / (256 * 8), 256, 0, stream>>>(x, xb);
  // 1) qkv = xb @ w_attn + b_attn, RoPE fused (HW trig) into the q/k epilogue
  mfma_gemm<1><<<dim3((3 * C_) / 128, (B_ * T_) / 128), 256, 0, stream>>>(
      xb, waT, b_attn, qP, kP, vP, nullptr, 3 * C_, C_);
  // 2) V transpose for conflict-free flash staging
  v_transpose<<<dim3(T_ / 64, B_ * H_), 256, 0, stream>>>(vP, vT);
  // 3) causal flash attention v6 (verified 47.8us)
  flash_mfma6<<<dim3(16, B_ * H_), 256, 0, stream>>>(qP, kP, vT);
  // 4) out = y @ w_proj + b_proj (fp32 out)
  mfma_gemm<0><<<dim3(C_ / 128, (B_ * T_) / 128), 256, 0, stream>>>(
      qP, wpT, b_proj, nullptr, nullptr, nullptr, out, C_, C_);
}

// Round 8
// 183.086 us; speedup vs baseline: 1.4923x; 1.0457x over previous
//
#include <hip/hip_runtime.h>
#include <hip/hip_bf16.h>

#define B_ 2
#define T_ 2048
#define C_ 1024
#define H_ 16
#define D_ 64

typedef __attribute__((ext_vector_type(8))) short bf16x8;
typedef __attribute__((ext_vector_type(4))) float f32x4;

static __device__ __forceinline__ float bf2f(unsigned short u) {
  union { unsigned int i; float f; } c;
  c.i = ((unsigned int)u) << 16;
  return c.f;
}
static __device__ __forceinline__ unsigned short f2bf(float f) {
  union { float f; unsigned int i; } c;
  c.f = f;
  unsigned int x = c.i;
  return (unsigned short)((x + 0x7fffu + ((x >> 16) & 1u)) >> 16);  // RNE
}

// async global->LDS, 16B per lane; LDS dest = (wave-uniform base) + lane*16
static __device__ __forceinline__ void gl_lds16(const void* g, void* s) {
  __builtin_amdgcn_global_load_lds(
      (const __attribute__((address_space(1))) void*)g,
      (__attribute__((address_space(3))) void*)s, 16, 0, 0);
}

// ---------------------------------------------------------------------------
__global__ __launch_bounds__(256) void fill_kernel_f32(float* __restrict__ out,
                                                       int n, float v) {
  int i = blockIdx.x * 256 + threadIdx.x;
  if (i < n) out[i] = v;
}

// ---------------------------------------------------------------------------
// Fused prep (saves 2 launches):
//   z=0: w_attn [1024][3072] -> waT [3072][1024] bf16   (96x32 tiles)
//   z=1: w_proj [1024][1024] -> wpT [1024][1024] bf16   (32x32 of the 96x32)
//   z=2: x fp32 -> xb bf16, 8 elems/thread              (2048 linear ids)
// ---------------------------------------------------------------------------
__global__ __launch_bounds__(256) void prep_kernel(
    const float* __restrict__ w_attn, const float* __restrict__ w_proj,
    const float* __restrict__ x,
    unsigned short* __restrict__ waT, unsigned short* __restrict__ wpT,
    unsigned short* __restrict__ xb) {
  __shared__ float tile[32][33];
  const int z = blockIdx.z;
  if (z == 2) {
    const int id = blockIdx.y * 96 + blockIdx.x;
    if (id >= 2048) return;
    int i = (id * 256 + threadIdx.x) * 8;
    float4 f0 = *(const float4*)(x + i);
    float4 f1 = *(const float4*)(x + i + 4);
    union { unsigned short u[8]; uint4 v; } p;
    p.u[0] = f2bf(f0.x); p.u[1] = f2bf(f0.y); p.u[2] = f2bf(f0.z); p.u[3] = f2bf(f0.w);
    p.u[4] = f2bf(f1.x); p.u[5] = f2bf(f1.y); p.u[6] = f2bf(f1.z); p.u[7] = f2bf(f1.w);
    *(uint4*)(xb + i) = p.v;
    return;
  }
  const float* W;
  unsigned short* WT;
  int Kd, Nd;
  if (z == 0) { W = w_attn; WT = waT; Kd = 1024; Nd = 3072; }
  else {
    if (blockIdx.x >= 32) return;
    W = w_proj; WT = wpT; Kd = 1024; Nd = 1024;
  }
  const int n0 = blockIdx.x * 32, k0 = blockIdx.y * 32;
  const int tx = threadIdx.x & 31, ty = threadIdx.x >> 5;  // ty 0..7
#pragma unroll
  for (int i = 0; i < 4; ++i)
    tile[ty + i * 8][tx] = W[(size_t)(k0 + ty + i * 8) * Nd + n0 + tx];
  __syncthreads();
#pragma unroll
  for (int i = 0; i < 4; ++i)
    WT[(size_t)(n0 + ty + i * 8) * Kd + k0 + tx] = f2bf(tile[tx][ty + i * 8]);
}

// ---------------------------------------------------------------------------
// Per-head V transpose: vP[b*T+t][h*64+d] -> vT[((b*16+h)*64+d)*2048 + t].
// ---------------------------------------------------------------------------
__global__ __launch_bounds__(256) void v_transpose(const unsigned short* __restrict__ vP,
                                                   unsigned short* __restrict__ vT) {
  __shared__ unsigned short tile[64][72];
  const int t0 = blockIdx.x * 64;
  const int bh = blockIdx.y;
  const int b = bh >> 4;
  const int srow = threadIdx.x >> 3;       // 0..31
  const int sc8 = (threadIdx.x & 7) * 8;
#pragma unroll
  for (int it = 0; it < 2; ++it) {
    int r = srow + it * 32;
    *(uint4*)&tile[r][sc8] =
        *(const uint4*)(vP + (size_t)(b * T_ + t0 + r) * 1024 + (bh & 15) * 64 + sc8);
  }
  __syncthreads();
#pragma unroll
  for (int it = 0; it < 2; ++it) {
    int dd = srow + it * 32;
    union { unsigned short u[8]; uint4 v; } o;
#pragma unroll
    for (int j = 0; j < 8; ++j) o.u[j] = tile[sc8 + j][dd];
    *(uint4*)(vT + ((size_t)bh * 64 + dd) * 2048 + t0 + sc8) = o.v;
  }
}

// ---------------------------------------------------------------------------
// MFMA GEMM: C = A(bf16)[M,K] @ BT(bf16)[N,K]^T + bias.
// 128x128 tile, BK=64, 4 waves, m97 staging (verified). v11: epilogues route
// the output tile through the post-loop-idle As/Bs LDS (S, 32KB exact) and
// store vectorized:
//   OUT_PLANES=1: RoPE fused (HW trig, verified v10) or plain v; values
//     written to S[128][128] bf16 then 8x uint4 coalesced stores/thread.
//   OUT_PLANES=0: fp32 via two 64-row passes of S (float view) then 8x
//     float4 stores/thread per pass.
// Per-16-lane phase the LDS reads are one contiguous 256B row -> conflict-
// free without swizzle; writes are <=4-way on cheap scalar LDS ops.
// ---------------------------------------------------------------------------
template <int OUT_PLANES>
__global__ __launch_bounds__(256) void mfma_gemm(
    const unsigned short* __restrict__ A,
    const unsigned short* __restrict__ BT,
    const float* __restrict__ bias,
    unsigned short* __restrict__ qP, unsigned short* __restrict__ kP,
    unsigned short* __restrict__ vP, float* __restrict__ Fout,
    int N, int K) {
  __shared__ unsigned short S[128 * 128];   // loop: As = S[0:8192), Bs = S[8192:16384)
  unsigned short* As = S;
  unsigned short* Bs = S + 128 * 64;

  const int tid = threadIdx.x;
  const int w = tid >> 6, lane = tid & 63;
  const int lo = lane & 15, g = lane >> 4;
  const int wm = (w >> 1) * 64, wn = (w & 1) * 64;
  const int m0 = blockIdx.y * 128, n0 = blockIdx.x * 128;

  const int lr8 = lane >> 3;           // row within the 8-row instr span

  const f32x4 zero4 = {0.f, 0.f, 0.f, 0.f};
  f32x4 acc[4][4] = {{zero4, zero4, zero4, zero4}, {zero4, zero4, zero4, zero4},
                     {zero4, zero4, zero4, zero4}, {zero4, zero4, zero4, zero4}};

  for (int k0 = 0; k0 < K; k0 += 64) {
    __syncthreads();  // previous iteration's frag readers done
#pragma unroll
    for (int it = 0; it < 4; ++it) {
      const int base_row = w * 32 + it * 8;       // wave-uniform
      const int r = base_row + lr8;               // this lane's row
      const int j = (lane & 7) ^ (r & 7);         // global chunk for LDS chunk lane&7
      gl_lds16(A + (size_t)(m0 + r) * K + k0 + j * 8, &As[base_row * 64]);
      gl_lds16(BT + (size_t)(n0 + r) * K + k0 + j * 8, &Bs[base_row * 64]);
    }
    __syncthreads();  // drains vmcnt -> staging visible

#pragma unroll
    for (int kk = 0; kk < 2; ++kk) {
      bf16x8 af[4], bfr[4];
#pragma unroll
      for (int i = 0; i < 4; ++i) {
        int ra = wm + i * 16 + lo;
        int rb = wn + i * 16 + lo;
        af[i]  = *(const bf16x8*)&As[ra * 64 + ((g + kk * 4) ^ (ra & 7)) * 8];
        bfr[i] = *(const bf16x8*)&Bs[rb * 64 + ((g + kk * 4) ^ (rb & 7)) * 8];
      }
#pragma unroll
      for (int i = 0; i < 4; ++i)
#pragma unroll
        for (int j = 0; j < 4; ++j)
          acc[i][j] = __builtin_amdgcn_mfma_f32_16x16x32_bf16(af[i], bfr[j],
                                                              acc[i][j], 0, 0, 0);
    }
  }

  float bv[4];
#pragma unroll
  for (int j = 0; j < 4; ++j) bv[j] = bias[n0 + wn + j * 16 + lo];

  if (OUT_PLANES) {
    const int pl = n0 >> 10;
    __syncthreads();  // all frag readers done; S reusable
    if (pl == 2) {
      // ---- v plane: values -> S bf16
#pragma unroll
      for (int i = 0; i < 4; ++i)
#pragma unroll
        for (int r = 0; r < 4; ++r) {
          const int row = wm + i * 16 + g * 4 + r;
#pragma unroll
          for (int j = 0; j < 4; ++j)
            S[row * 128 + wn + j * 16 + lo] = f2bf(acc[i][j][r] + bv[j]);
        }
    } else {
      // ---- q/k planes: fused RoPE (HW trig in revolutions; v10-verified)
      const float scale = (pl == 0) ? 0.125f : 1.0f;
      const float invA = exp2f((float)(-2 * lo) * (13.287712379549449f / 64.0f)) *
                         0.15915494309189535f;
      const float invB = exp2f((float)(-2 * (lo + 16)) * (13.287712379549449f / 64.0f)) *
                         0.15915494309189535f;
      const int c0 = wn + lo;
#pragma unroll
      for (int i = 0; i < 4; ++i)
#pragma unroll
        for (int r = 0; r < 4; ++r) {
          const int row = wm + i * 16 + g * 4 + r;
          const float t = (float)((m0 + row) & (T_ - 1));
          float ra = t * invA; ra -= floorf(ra);    // [0,1) revolutions
          float rb = t * invB; rb -= floorf(rb);
          const float sA = __builtin_amdgcn_sinf(ra);
          const float cA = __builtin_amdgcn_cosf(ra);
          const float sB = __builtin_amdgcn_sinf(rb);
          const float cB = __builtin_amdgcn_cosf(rb);
          const float q1A = acc[i][0][r] + bv[0];
          const float q2A = acc[i][2][r] + bv[2];
          const float q1B = acc[i][1][r] + bv[1];
          const float q2B = acc[i][3][r] + bv[3];
          S[row * 128 + c0]      = f2bf((q1A * cA - q2A * sA) * scale);
          S[row * 128 + c0 + 32] = f2bf((q2A * cA + q1A * sA) * scale);
          S[row * 128 + c0 + 16] = f2bf((q1B * cB - q2B * sB) * scale);
          S[row * 128 + c0 + 48] = f2bf((q2B * cB + q1B * sB) * scale);
        }
    }
    __syncthreads();
    // ---- vectorized store: 8x uint4/thread, coalesced
    unsigned short* P = (pl == 0) ? qP : (pl == 1) ? kP : vP;
    const int pcol0 = n0 & 1023;
#pragma unroll
    for (int it2 = 0; it2 < 8; ++it2) {
      const int p = it2 * 256 + tid;          // uint4 index 0..2047
      const int lrow = p >> 4;                // 128 rows x 16 uint4
      const int lcol = (p & 15) * 8;
      uint4 v4 = *(const uint4*)&S[lrow * 128 + lcol];
      *(uint4*)(P + (size_t)(m0 + lrow) * 1024 + pcol0 + lcol) = v4;
    }
  } else {
    // ---- fp32 out via two 64-row LDS passes (S as float[64][128])
    float* Sf = (float*)S;
#pragma unroll
    for (int hh = 0; hh < 2; ++hh) {
      __syncthreads();
      if ((w >> 1) == hh) {
#pragma unroll
        for (int i = 0; i < 4; ++i)
#pragma unroll
          for (int r = 0; r < 4; ++r) {
            const int lrow = i * 16 + g * 4 + r;
#pragma unroll
            for (int j = 0; j < 4; ++j)
              Sf[lrow * 128 + wn + j * 16 + lo] = acc[i][j][r] + bv[j];
          }
      }
      __syncthreads();
#pragma unroll
      for (int it2 = 0; it2 < 8; ++it2) {
        const int p = it2 * 256 + tid;        // float4 index 0..2047
        const int lrow = p >> 5;              // 64 rows x 32 float4
        const int lcol = (p & 31) * 4;
        float4 v4 = *(const float4*)&Sf[lrow * 128 + lcol];
        *(float4*)(Fout + (size_t)(m0 + hh * 64 + lrow) * N + n0 + lcol) = v4;
      }
    }
  }
}

// ---------------------------------------------------------------------------
// flash v11 = flash_mfma6 (verified 46.3us; paired tiles, swapped QK^T, b64
// P-write, scalar lsum, setprio, double-barrier staging + reg prefetch) with
// an XCD-chunked flat grid (decode correctness-proven in v7): each XCD serves
// only 4 bh pairs -> ~3MB K/V/q working set fits the 4MB XCD L2 (natural
// round-robin spread all 32 bh over every XCD = 16MB thrash; FETCH_SIZE was
// 122MB vs 32MB logical).
// ---------------------------------------------------------------------------
__global__ __launch_bounds__(256) void flash_mfma6(
    unsigned short* __restrict__ qP,
    const unsigned short* __restrict__ kP,
    const unsigned short* __restrict__ vT) {
  const int cid = blockIdx.x;            // 0..511
  const int xcd = cid & 7;
  const int k6 = cid >> 3;               // 0..63
  const int bh = xcd * 4 + (k6 >> 4);    // 4 bh per XCD
  const int bx = k6 & 15;                // 0..15
  const int b = bh >> 4, h = bh & 15;
  const int tid = threadIdx.x;
  const int w = tid >> 6, lane = tid & 63;
  const int lo = lane & 15, g = lane >> 4;

  __shared__ unsigned short Ks[64][72];   // [key][d]
  __shared__ unsigned short VTs[64][72];  // [d][key]
  __shared__ unsigned short Ps[64][72];   // [q][key]

  const int srow = tid >> 3;        // 0..31
  const int sc8 = (tid & 7) * 8;
  const f32x4 zero4 = {0.f, 0.f, 0.f, 0.f};

#pragma unroll
  for (int half = 0; half < 2; ++half) {
    const int qt = half ? (31 - bx) : bx;
    const int rowq0 = b * T_ + qt * 64;

    // Q fragments for this wave's 16 q-rows (B-operand of swapped QK).
    const unsigned short* qrow = qP + (size_t)(rowq0 + w * 16 + lo) * 1024 + h * 64;
    bf16x8 aq0 = *(const bf16x8*)(qrow + g * 8);
    bf16x8 aq1 = *(const bf16x8*)(qrow + 32 + g * 8);

    f32x4 oacc[4] = {zero4, zero4, zero4, zero4};  // O[q=w*16+g*4+r][d=c2*16+lo]
    float lsum = 0.f;                              // denom partial, q = w*16+lo

    uint4 kreg0, kreg1, vreg0, vreg1;
    {
      const size_t kb = (size_t)(b * T_ + srow) * 1024 + h * 64 + sc8;
      kreg0 = *(const uint4*)(kP + kb);
      kreg1 = *(const uint4*)(kP + kb + (size_t)32 * 1024);
      const size_t vb = ((size_t)bh * 64 + srow) * 2048 + sc8;
      vreg0 = *(const uint4*)(vT + vb);
      vreg1 = *(const uint4*)(vT + vb + (size_t)32 * 2048);
    }

    for (int kt = 0; kt <= qt; ++kt) {
      __syncthreads();   // prior readers of Ks/VTs/Ps done
      *(uint4*)&Ks[srow][sc8]       = kreg0;
      *(uint4*)&Ks[srow + 32][sc8]  = kreg1;
      *(uint4*)&VTs[srow][sc8]      = vreg0;
      *(uint4*)&VTs[srow + 32][sc8] = vreg1;
      __syncthreads();   // staging visible
      if (kt < qt) {
        const size_t kb = (size_t)(b * T_ + (kt + 1) * 64 + srow) * 1024 + h * 64 + sc8;
        kreg0 = *(const uint4*)(kP + kb);
        kreg1 = *(const uint4*)(kP + kb + (size_t)32 * 1024);
        const size_t vb = ((size_t)bh * 64 + srow) * 2048 + (kt + 1) * 64 + sc8;
        vreg0 = *(const uint4*)(vT + vb);
        vreg1 = *(const uint4*)(vT + vb + (size_t)32 * 2048);
      }

      // ---- swapped QK^T: sacc[ct][r] = S^T[k=ct*16+g*4+r][q=w*16+lo]
      f32x4 sacc[4] = {zero4, zero4, zero4, zero4};
      __builtin_amdgcn_s_setprio(1);
#pragma unroll
      for (int ct = 0; ct < 4; ++ct) {
        bf16x8 bk0 = *(const bf16x8*)&Ks[ct * 16 + lo][g * 8];
        bf16x8 bk1 = *(const bf16x8*)&Ks[ct * 16 + lo][32 + g * 8];
        sacc[ct] = __builtin_amdgcn_mfma_f32_16x16x32_bf16(bk0, aq0, sacc[ct], 0, 0, 0);
        sacc[ct] = __builtin_amdgcn_mfma_f32_16x16x32_bf16(bk1, aq1, sacc[ct], 0, 0, 0);
      }
      __builtin_amdgcn_s_setprio(0);

      // ---- causal mask (diagonal tile only): local k > local q -> -inf
      if (kt == qt) {
#pragma unroll
        for (int ct = 0; ct < 4; ++ct)
#pragma unroll
          for (int r = 0; r < 4; ++r)
            if (ct * 16 + g * 4 + r > w * 16 + lo) sacc[ct][r] = -1e30f;
      }

      // ---- exp + lsum + vectorized P-write (k consecutive in-lane)
#pragma unroll
      for (int ct = 0; ct < 4; ++ct) {
        float p0 = __expf(sacc[ct][0]);
        float p1 = __expf(sacc[ct][1]);
        float p2 = __expf(sacc[ct][2]);
        float p3 = __expf(sacc[ct][3]);
        lsum += (p0 + p1) + (p2 + p3);
        unsigned int u0 = (unsigned int)f2bf(p0) | ((unsigned int)f2bf(p1) << 16);
        unsigned int u1 = (unsigned int)f2bf(p2) | ((unsigned int)f2bf(p3) << 16);
        uint2 pw; pw.x = u0; pw.y = u1;
        *(uint2*)&Ps[w * 16 + lo][ct * 16 + g * 4] = pw;
      }

      // ---- PV (same-wave Ps write->read, in-order DS pipe)
      bf16x8 ap0 = *(const bf16x8*)&Ps[w * 16 + lo][g * 8];
      bf16x8 ap1 = *(const bf16x8*)&Ps[w * 16 + lo][32 + g * 8];
      __builtin_amdgcn_s_setprio(1);
#pragma unroll
      for (int c2 = 0; c2 < 4; ++c2) {
        bf16x8 bv0 = *(const bf16x8*)&VTs[c2 * 16 + lo][g * 8];
        bf16x8 bv1 = *(const bf16x8*)&VTs[c2 * 16 + lo][32 + g * 8];
        oacc[c2] = __builtin_amdgcn_mfma_f32_16x16x32_bf16(ap0, bv0, oacc[c2], 0, 0, 0);
        oacc[c2] = __builtin_amdgcn_mfma_f32_16x16x32_bf16(ap1, bv1, oacc[c2], 0, 0, 0);
      }
      __builtin_amdgcn_s_setprio(0);
    }

    // ---- denominator: reduce over g (lanes with same lo), then per-r pickup
    lsum += __shfl_xor(lsum, 16);
    lsum += __shfl_xor(lsum, 32);   // lanes {lo,lo+16,lo+32,lo+48}: full denom

#pragma unroll
    for (int r = 0; r < 4; ++r) {
      float inv_r = 1.0f / __shfl(lsum, g * 4 + r);  // lane s holds q=w*16+s
      unsigned short* dst = qP + (size_t)(rowq0 + w * 16 + g * 4 + r) * 1024 + h * 64 + lo;
#pragma unroll
      for (int c2 = 0; c2 < 4; ++c2)
        dst[c2 * 16] = f2bf(oacc[c2][r] * inv_r);
    }
    // next half's first __syncthreads protects LDS reuse vs these stores
  }
}

// ---------------------------------------------------------------------------
extern "C" void kernel_launch(void* const* d_in, const int* in_sizes, int n_in,
                              void* d_out, int out_size, void* d_ws, size_t ws_size,
                              hipStream_t stream) {
  const float *x = nullptr, *w_attn = nullptr, *b_attn = nullptr,
              *w_proj = nullptr, *b_proj = nullptr;
  for (int i = 0; i < n_in; ++i) {
    switch (in_sizes[i]) {
      case B_ * T_ * C_:  x      = (const float*)d_in[i]; break;
      case C_ * 3 * C_:   w_attn = (const float*)d_in[i]; break;
      case 3 * C_:        b_attn = (const float*)d_in[i]; break;
      case C_ * C_:       w_proj = (const float*)d_in[i]; break;
      case C_:            b_proj = (const float*)d_in[i]; break;
      default: break;
    }
  }
  float* out = (float*)d_out;
  const int nblk = (out_size + 255) / 256;

  if (!x || !w_attn || !b_attn || !w_proj || !b_proj) {
    fill_kernel_f32<<<nblk, 256, 0, stream>>>(out, out_size, 100.0f);  // SENTINEL
    return;
  }
  // ws >= 48 MB proven (rounds 10/11 fast path). Sentinel otherwise.
  if (ws_size < (size_t)48 * 1024 * 1024) {
    fill_kernel_f32<<<nblk, 256, 0, stream>>>(out, out_size, 50.0f);   // SENTINEL
    return;
  }

  // layout: q|k|v planes (24 MB) | vT (8) | xb (8) | waT (6) | wpT (2) = 48 MB
  unsigned short* qP  = (unsigned short*)d_ws;
  unsigned short* kP  = qP + (size_t)(B_ * T_) * 1024;
  unsigned short* vP  = kP + (size_t)(B_ * T_) * 1024;
  unsigned short* vT  = vP + (size_t)(B_ * T_) * 1024;
  unsigned short* xb  = vT + (size_t)(B_ * T_) * 1024;
  unsigned short* waT = xb + (size_t)(B_ * T_) * C_;
  unsigned short* wpT = waT + (size_t)C_ * 3 * C_;

  // 0) fused prep: weight transposes + x conversion (one launch)
  prep_kernel<<<dim3(96, 32, 3), 256, 0, stream>>>(w_attn, w_proj, x, waT, wpT, xb);
  // 1) qkv = xb @ w_attn + b_attn, RoPE fused (HW trig), vectorized epilogue
  mfma_gemm<1><<<dim3((3 * C_) / 128, (B_ * T_) / 128), 256, 0, stream>>>(
      xb, waT, b_attn, qP, kP, vP, nullptr, 3 * C_, C_);
  // 2) V transpose for conflict-free flash staging
  v_transpose<<<dim3(T_ / 64, B_ * H_), 256, 0, stream>>>(vP, vT);
  // 3) causal flash attention (XCD-chunked grid)
  flash_mfma6<<<dim3(512), 256, 0, stream>>>(qP, kP, vT);
  // 4) out = y @ w_proj + b_proj (fp32 out, vectorized epilogue)
  mfma_gemm<0><<<dim3(C_ / 128, (B_ * T_) / 128), 256, 0, stream>>>(
      qP, wpT, b_proj, nullptr, nullptr, nullptr, out, C_, C_);
}